// Round 14
// baseline (458.233 us; speedup 1.0000x reference)
//
#include <hip/hip_runtime.h>
#include <math.h>

#define B_    8
#define SEQ_  8192
#define D_    512
#define N_    1023
#define DWT_  511
#define DFF_  2048
#define MR_   (B_ * DWT_)          // 4088 rows for all [B*L, D] GEMMs

// ---------------- d_out layout (flat concat of the 5 outputs) ----------------
#define PREDS_O    0
#define RECON_O    768
#define RECON_LEN  1022
#define PATCHES_O  (RECON_O + 8*512*1022)   // 4186880
#define OUT_LL_O   (PATCHES_O + 8*512*1023) // 8377088
#define OUT_LH_O   (OUT_LL_O + 8*512*511)   // 10470144

// ---------------- workspace layout (float units) ----------------
#define WS_MEAN   ((size_t)0)
#define WS_STD    ((size_t)8)
#define WS_XN     ((size_t)16)
#define WS_PSEQ   ((size_t)65552)
#define WS_LLSEQ  ((size_t)4255760)    // bf16 [4088][512]
#define WS_LHSEQ  ((size_t)6348816)    // bf16
#define WS_CROSS  ((size_t)21000208)   // bf16 [4088][512] (cross16)
#define WS_GATE   ((size_t)23093264)
#define WS_LLF    ((size_t)23097352)   // bf16 [4088][512]
#define WS_LHF    ((size_t)25190408)   // bf16
#define WS_LLO    ((size_t)16814096)   // fp32 [4088][512] (MLP out, LL)
#define WS_LHO    ((size_t)18907152)   // fp32 (LH)
#define WS_PART   WS_CROSS             // head partials alias cross (disjoint phase)
// bf16 buffers beyond the old arena (ws ~766MiB)
#define WS_QB     ((size_t)27283464)   // 2 x [4088][512] bf16
#define WS_KB     (WS_QB + 2093056)
#define WS_VT     (WS_KB + 2093056)    // 2 x [4096][512] bf16
#define WS_OB     (WS_VT + 2097152)
#define WS_HID2   (WS_OB + 2093056)    // 2 x [4088][2048] bf16
#define WS_LLO16  (WS_HID2 + 8372224)  // 2 x [4088][512] bf16 (llout16, lhout16)
#define WS_WT     ((size_t)48218120)   // bf16 weight arena (own region, no alias!)

using bf16x8 = __attribute__((ext_vector_type(8))) short;
using u16x8  = __attribute__((ext_vector_type(8))) unsigned short;
using f32x4  = __attribute__((ext_vector_type(4))) float;

__device__ inline unsigned short f2bf(float f) {
  unsigned u = __float_as_uint(f);
  u += 0x7fffu + ((u >> 16) & 1u);    // round-to-nearest-even
  return (unsigned short)(u >> 16);
}
__device__ inline float bf2f(unsigned short h) {
  return __uint_as_float(((unsigned)h) << 16);
}

// async global->LDS DMA, 16B per lane; lds base must be wave-uniform.
__device__ __forceinline__ void gld16(const void* g, void* lds) {
  __builtin_amdgcn_global_load_lds(
      (const __attribute__((address_space(1))) unsigned int*)g,
      (__attribute__((address_space(3))) unsigned int*)lds, 16, 0, 0);
}

// ---------------------------------------------------------------------------
__global__ __launch_bounds__(256) void k_revin(const float* __restrict__ x,
    const float* __restrict__ rw, const float* __restrict__ rb,
    float* __restrict__ meanp, float* __restrict__ stdp, float* __restrict__ xn)
{
  __shared__ float rs[256], rs2[256];
  int b = blockIdx.x, tid = threadIdx.x;
  const float* xb = x + (size_t)b * SEQ_;
  float s = 0.f, s2 = 0.f;
  for (int i = tid; i < SEQ_; i += 256) { float v = xb[i]; s += v; s2 += v * v; }
  rs[tid] = s; rs2[tid] = s2; __syncthreads();
  for (int o = 128; o > 0; o >>= 1) {
    if (tid < o) { rs[tid] += rs[tid + o]; rs2[tid] += rs2[tid + o]; }
    __syncthreads();
  }
  float mu = rs[0] / SEQ_;
  float var = rs2[0] / SEQ_ - mu * mu;
  float sd = sqrtf(var + 1e-5f);
  if (tid == 0) { meanp[b] = mu; stdp[b] = sd; }
  float w = rw[0], bb = rb[0], inv = 1.f / sd;
  for (int i = tid; i < SEQ_; i += 256)
    xn[(size_t)b * SEQ_ + i] = (xb[i] - mu) * inv * w + bb;
}

// ---------------------------------------------------------------------------
// merged: blocks 0..8183 patch-embed; 8184..15351 weight transpose+convert.
__global__ __launch_bounds__(512) void k_pw(const float* __restrict__ xn,
    const float* __restrict__ pW, const float* __restrict__ pb,
    const float* __restrict__ pos, float* __restrict__ p_seq,
    const float* __restrict__ attn_W, const float* __restrict__ mlp_W1,
    const float* __restrict__ mlp_W2, unsigned short* __restrict__ wt,
    unsigned short* __restrict__ w1t, unsigned short* __restrict__ w2t)
{
  __shared__ float sx[16];
  __shared__ float tl[32][33];
  int bid = blockIdx.x, tid = threadIdx.x;
  if (bid < 8184) {
    int n = bid % N_, b = bid / N_, d = tid;
    if (tid < 16) sx[tid] = xn[(size_t)b * SEQ_ + n * 8 + tid];
    __syncthreads();
    float acc = pb[d] + pos[(size_t)n * D_ + d];
#pragma unroll
    for (int k = 0; k < 16; ++k) acc += sx[k] * pW[k * D_ + d];
    p_seq[((size_t)b * N_ + n) * D_ + d] = acc;
  } else {
    int b2 = bid - 8184;
    const float* src; unsigned short* dst; int K, N, nx, ky;
    if (b2 < 3072) {
      int z = b2 >> 8, r = b2 & 255;
      nx = r & 15; ky = r >> 4; K = 512; N = 512;
      src = attn_W + (size_t)z * 262144; dst = wt + (size_t)z * 262144;
    } else if (b2 < 5120) {
      int b3 = b2 - 3072; int z = b3 >> 10, r = b3 & 1023;
      nx = r & 63; ky = r >> 6; K = 512; N = 2048;
      src = mlp_W1 + (size_t)z * 1048576; dst = w1t + (size_t)z * 1048576;
    } else {
      int b4 = b2 - 5120; int z = b4 >> 10, r = b4 & 1023;
      nx = r & 15; ky = r >> 4; K = 2048; N = 512;
      src = mlp_W2 + (size_t)z * 1048576; dst = w2t + (size_t)z * 1048576;
    }
    int n0 = nx * 32, k0 = ky * 32;
    int tx = tid & 31, ty = tid >> 5;    // ty 0..15
#pragma unroll
    for (int r = 0; r < 2; ++r)
      tl[ty + 16 * r][tx] = src[(size_t)(k0 + ty + 16 * r) * N + n0 + tx];
    __syncthreads();
#pragma unroll
    for (int r = 0; r < 2; ++r)
      dst[(size_t)(n0 + ty + 16 * r) * K + k0 + tx] = f2bf(tl[tx][ty + 16 * r]);
  }
}

// ---------------------------------------------------------------------------
// merged: blocks 0..4095 transpose pseq -> patches; 4096..4351 DWT+gate with
// coalesced [d][t]-chunk writes (16 consecutive t per thread = 64B/lane).
__global__ __launch_bounds__(512) void k_td(const float* __restrict__ p_seq,
    float* __restrict__ patches, const float* __restrict__ h,
    const float* __restrict__ g, unsigned short* __restrict__ ll_seq,
    unsigned short* __restrict__ lh_seq, float* __restrict__ ll_out,
    float* __restrict__ lh_out, const float* __restrict__ raw_tau,
    float* __restrict__ gate)
{
  __shared__ float tile[32][33];
  __shared__ float gpart[16][8];
  int bid = blockIdx.x, tid = threadIdx.x;
  if (bid < 4096) {
    int d0 = (bid & 15) * 32, n0 = ((bid >> 4) & 31) * 32, b = bid >> 9;
    int tx = tid & 31, ty = tid >> 5;   // ty 0..15
#pragma unroll
    for (int r = 0; r < 2; ++r) {
      int n = n0 + ty + 16 * r;
      if (n < N_) tile[ty + 16 * r][tx] = p_seq[((size_t)b * N_ + n) * D_ + d0 + tx];
    }
    __syncthreads();
#pragma unroll
    for (int r = 0; r < 2; ++r) {
      int d = d0 + ty + 16 * r, n = n0 + tx;
      if (n < N_) patches[((size_t)b * D_ + d) * N_ + n] = tile[tx][ty + 16 * r];
    }
  } else {
    int idx = bid - 4096;               // 0..255
    int b = idx >> 5, tt = idx & 31;
    int t0 = tt << 4;
    int d = tid;
    float h4[4], g4[4];
#pragma unroll
    for (int k = 0; k < 4; ++k) { h4[k] = h[d * 4 + k]; g4[k] = g[d * 4 + k]; }
    float llv[16], lhv[16], av[16];
#pragma unroll
    for (int i = 0; i < 16; ++i) {
      int t = t0 + i;
      float ah = 0.f, ag = 0.f;
      if (t < DWT_) {
#pragma unroll
        for (int k = 0; k < 4; ++k) {
          int n = 2 * t + k - 1;
          if (n >= 0 && n < N_) {
            float v = p_seq[((size_t)b * N_ + n) * D_ + d];
            ah += v * h4[k]; ag += v * g4[k];
          }
        }
      }
      llv[i] = ah; lhv[i] = ag; av[i] = fabsf(ag);
    }
    // bf16 sequence writes ([t][d]-major, coalesced)
#pragma unroll
    for (int i = 0; i < 16; ++i) {
      int t = t0 + i;
      if (t < DWT_) {
        ll_seq[((size_t)b * DWT_ + t) * D_ + d] = f2bf(llv[i]);
        lh_seq[((size_t)b * DWT_ + t) * D_ + d] = f2bf(lhv[i]);
      }
    }
    // fp32 d_out writes: 16 consecutive t per thread = one 64B line per lane
    size_t ob = ((size_t)b * D_ + d) * DWT_ + t0;
#pragma unroll
    for (int i = 0; i < 16; ++i) {
      if (t0 + i < DWT_) { ll_out[ob + i] = llv[i]; lh_out[ob + i] = lhv[i]; }
    }
    // gate: butterfly-reduce each of 16 t's across the wave, then LDS combine
#pragma unroll
    for (int off = 1; off < 64; off <<= 1)
#pragma unroll
      for (int i = 0; i < 16; ++i) av[i] += __shfl_xor(av[i], off);
    int lane = tid & 63, w = tid >> 6;
    if (lane == 0) {
#pragma unroll
      for (int i = 0; i < 16; ++i) gpart[i][w] = av[i];
    }
    __syncthreads();
    if (tid < 16) {
      float s = 0.f;
#pragma unroll
      for (int w2 = 0; w2 < 8; ++w2) s += gpart[tid][w2];
      int t = t0 + tid;
      if (t < DWT_) {
        float tau = 1.f / (1.f + expf(-raw_tau[0]));
        float e = s / (float)D_;
        gate[(size_t)b * DWT_ + t] = 1.f / (1.f + expf(-(e - tau) * 10.f));
      }
    }
  }
}

// ---------------------------------------------------------------------------
// C = A(bf16) @ WT(bf16 [N][K])^T + bias (+res) (opt gelu) via MFMA, z-batched.
// 2-phase double-buffered K-loop with counted vmcnt (DMA stays in flight).
// CMODE 0: fp32 C[m][n] (+res; RESBF: residual bf16). 1: bf16 C[m][n].
// CMODE 3: fused QKV: n<512->Q bf16; <1024->K bf16; >=1024->V transposed.
template<int BM, int CMODE, int RESBF = 0>
__global__ __launch_bounds__(256, BM == 64 ? 3 : 2) void k_gemm_mfma(
    const void* __restrict__ A00, const void* __restrict__ A01,
    const void* __restrict__ A10, const void* __restrict__ A11,
    const unsigned short* __restrict__ WT, const float* __restrict__ bias,
    const void* __restrict__ res0, const void* __restrict__ res1,
    void* __restrict__ C0, void* __restrict__ C1, void* __restrict__ C2,
    int M, int N, int K, int act, int zsW, int zsB)
{
  __shared__ unsigned char lds[2][(BM + 128) * 128];

  const int tid = threadIdx.x;
  const int wid = tid >> 6, lane = tid & 63;
  const int n0 = blockIdx.x * 128, m0 = blockIdx.y * BM;
  const int z = blockIdx.z;
  constexpr int MI = 4;
  constexpr int NI = (BM == 128) ? 4 : 2;
  const int wrow = (BM == 128) ? (wid >> 1) * 64 : 0;
  const int wcol = (BM == 128) ? (wid & 1) * 64 : wid * 32;
  const int l16 = lane & 15, lh = lane >> 4;

  const unsigned short* wt_ = WT + (size_t)z * zsW;
  const float* bias_ = bias + (size_t)z * zsB;
  const unsigned short* Ap;
  if (CMODE == 3) Ap = (const unsigned short*)(z ? (n0 < 512 ? A10 : A11)
                                                 : (n0 < 512 ? A00 : A01));
  else            Ap = (const unsigned short*)(z ? A10 : A00);

  f32x4 acc[MI][NI];
#pragma unroll
  for (int i = 0; i < MI; ++i)
#pragma unroll
    for (int j = 0; j < NI; ++j) acc[i][j] = (f32x4){0.f, 0.f, 0.f, 0.f};

  const int nk = K >> 6;
  auto stage = [&](int t, int buf) {
    unsigned char* sA = lds[buf];
    unsigned char* sB = lds[buf] + BM * 128;
    int k0 = t << 6;
    constexpr int PA = BM / 32;
#pragma unroll
    for (int p = 0; p < PA; ++p) {
      int s0 = wid * (BM * 2) + p * 64;
      int s = s0 + lane;
      int row = s >> 3, oct = s & 7;
      int gr = m0 + row; if (gr > M - 1) gr = M - 1;
      gld16(Ap + (size_t)gr * K + k0 + ((oct ^ (row & 7)) << 3),
            sA + (size_t)s0 * 16);
    }
#pragma unroll
    for (int p = 0; p < 4; ++p) {
      int s0 = wid * 256 + p * 64;
      int s = s0 + lane;
      int row = s >> 3, oct = s & 7;
      gld16(wt_ + (size_t)(n0 + row) * K + k0 + ((oct ^ (row & 7)) << 3),
            sB + (size_t)s0 * 16);
    }
  };

  stage(0, 0);
  for (int t = 0; t < nk; ++t) {
    const int cur = t & 1;
    if (t + 1 < nk) {
      stage(t + 1, cur ^ 1);
      if constexpr (BM == 64) asm volatile("s_waitcnt vmcnt(6)" ::: "memory");
      else                    asm volatile("s_waitcnt vmcnt(8)" ::: "memory");
    } else {
      asm volatile("s_waitcnt vmcnt(0)" ::: "memory");
    }
    __builtin_amdgcn_sched_barrier(0);
    __builtin_amdgcn_s_barrier();
    __builtin_amdgcn_sched_barrier(0);
    unsigned char* sA = lds[cur];
    unsigned char* sB = lds[cur] + BM * 128;
#pragma unroll
    for (int s = 0; s < 2; ++s) {
      bf16x8 af[MI], bfr[NI];
#pragma unroll
      for (int i = 0; i < MI; ++i) {
        int r = wrow + i * 16 + l16;
        af[i] = *(const bf16x8*)(sA + r * 128 + (((s * 4 + lh) ^ (r & 7)) << 4));
      }
#pragma unroll
      for (int j = 0; j < NI; ++j) {
        int r = wcol + j * 16 + l16;
        bfr[j] = *(const bf16x8*)(sB + r * 128 + (((s * 4 + lh) ^ (r & 7)) << 4));
      }
#pragma unroll
      for (int i = 0; i < MI; ++i)
#pragma unroll
        for (int j = 0; j < NI; ++j)
          acc[i][j] = __builtin_amdgcn_mfma_f32_16x16x32_bf16(af[i], bfr[j],
                                                              acc[i][j], 0, 0, 0);
    }
    __builtin_amdgcn_sched_barrier(0);
    __builtin_amdgcn_s_barrier();
  }
  // ---- epilogue ----
  const void* res_ = z ? res1 : res0;
#pragma unroll
  for (int i = 0; i < MI; ++i) {
#pragma unroll
    for (int r = 0; r < 4; ++r) {
      int m = m0 + wrow + i * 16 + lh * 4 + r;
      if (m >= M) continue;
#pragma unroll
      for (int j = 0; j < NI; ++j) {
        int n = n0 + wcol + j * 16 + l16;
        float v = acc[i][j][r] + bias_[n];
        if (act) v = 0.5f * v * (1.f + erff(v * 0.70710678118654752f));
        if (CMODE == 0) {
          float* Cp = (float*)(z ? C1 : C0);
          if (res_) {
            float rv = RESBF ? bf2f(((const unsigned short*)res_)[(size_t)m * N + n])
                             : ((const float*)res_)[(size_t)m * N + n];
            v += rv;
          }
          Cp[(size_t)m * N + n] = v;
        } else if (CMODE == 1) {
          unsigned short* Cp = (unsigned short*)(z ? C1 : C0);
          Cp[(size_t)m * N + n] = f2bf(v);
        } else {
          if (n < 512) {
            ((unsigned short*)C0)[(size_t)z * 2093056 + (size_t)m * 512 + n] = f2bf(v);
          } else if (n < 1024) {
            ((unsigned short*)C1)[(size_t)z * 2093056 + (size_t)m * 512 + (n - 512)] = f2bf(v);
          } else {
            int bb = m / DWT_;
            int key = m - bb * DWT_;
            ((unsigned short*)C2)[(size_t)z * 2097152 +
                ((size_t)(bb * 512 + (n - 1024))) * 512 + key] = f2bf(v);
          }
        }
      }
    }
  }
}

// ---------------------------------------------------------------------------
// MFMA flash attention, z-batched, register-prefetched K/V staging (T14).
__global__ __launch_bounds__(256) void k_mattn(
    const unsigned short* __restrict__ Qb, const unsigned short* __restrict__ Kb,
    const unsigned short* __restrict__ Vt, const float* __restrict__ gate,
    unsigned short* __restrict__ Ob)
{
  __shared__ unsigned char sQ[8192], sK[8192], sV[8192], sP[8192];
  __shared__ float sG[64];

  const int bh = blockIdx.x;
  const int b = bh >> 3;
  const int q0 = blockIdx.y * 64;
  const int z = blockIdx.z;
  const int tid = threadIdx.x;
  const int w = tid >> 6, lane = tid & 63;
  const int l16 = lane & 15, lh = lane >> 4;
  const bool hg = (z == 1) && (gate != nullptr);
  const int bD = b * DWT_;

  const unsigned short* Qz = Qb + (size_t)z * 2093056;
  const unsigned short* Kz = Kb + (size_t)z * 2093056;
  const unsigned short* Vz = Vt + (size_t)z * 2097152;
  unsigned short* Oz = Ob + (size_t)z * 2093056;
  const int h64 = (bh & 7) * 64;
  const unsigned short* vrow = Vz + (size_t)bh * 64 * 512;

  // stage Q tile [64 q][64 d]
#pragma unroll
  for (int it = 0; it < 2; ++it) {
    int i = it * 256 + tid;
    int row = i >> 3, oct = i & 7;
    int qr = q0 + row; if (qr > DWT_ - 1) qr = DWT_ - 1;
    u16x8 v = *(const u16x8*)(Qz + (size_t)(bD + qr) * 512 + h64 + oct * 8);
    *(u16x8*)(sQ + row * 128 + ((oct ^ (row & 7)) << 4)) = v;
  }

  // preload full gate vector (2 keys per thread)
  float ga = 0.f, gb2 = 0.f;
  if (hg) {
    int k = 2 * tid;
    ga  = (k     < DWT_) ? gate[(size_t)bD + k]     : 0.f;
    gb2 = (k + 1 < DWT_) ? gate[(size_t)bD + k + 1] : 0.f;
  }

  float m_ = -1e30f, l_ = 0.f;
  f32x4 accO[4];
#pragma unroll
  for (int jb = 0; jb < 4; ++jb) accO[jb] = (f32x4){0.f, 0.f, 0.f, 0.f};

  unsigned char* sPw = sP + w * 2048;   // wave-private [16 q][64 key] bf16

  uint4 pk0, pk1, pv0, pv1;
#define LOADT(kt_) do {                                                      \
    int k0_ = (kt_) * 64;                                                    \
    int row_ = tid >> 3, oct_ = tid & 7;                                     \
    int kr0_ = k0_ + row_;      if (kr0_ > DWT_ - 1) kr0_ = DWT_ - 1;        \
    int kr1_ = k0_ + row_ + 32; if (kr1_ > DWT_ - 1) kr1_ = DWT_ - 1;        \
    pk0 = *(const uint4*)(Kz + (size_t)(bD + kr0_) * 512 + h64 + oct_ * 8);  \
    pk1 = *(const uint4*)(Kz + (size_t)(bD + kr1_) * 512 + h64 + oct_ * 8);  \
    pv0 = *(const uint4*)(vrow + (size_t)row_ * 512 + k0_ + oct_ * 8);       \
    pv1 = *(const uint4*)(vrow + (size_t)(row_ + 32) * 512 + k0_ + oct_ * 8);\
  } while (0)

  LOADT(0);
  for (int kt = 0; kt < 8; ++kt) {
    const int k0 = kt * 64;
    __syncthreads();                    // prior-iter PV reads complete
    {
      int row = tid >> 3, oct = tid & 7, row1 = (tid >> 3) + 32;
      *(uint4*)(sK + row  * 128 + ((oct ^ (row  & 7)) << 4)) = pk0;
      *(uint4*)(sK + row1 * 128 + ((oct ^ (row1 & 7)) << 4)) = pk1;
      *(uint4*)(sV + row  * 128 + ((oct ^ (row  & 7)) << 4)) = pv0;
      *(uint4*)(sV + row1 * 128 + ((oct ^ (row1 & 7)) << 4)) = pv1;
    }
    if (hg && (tid >> 5) == kt) {
      sG[(tid & 31) * 2]     = ga;
      sG[(tid & 31) * 2 + 1] = gb2;
    }
    __syncthreads();
    if (kt < 7) LOADT(kt + 1);          // prefetch next tile under compute

    // ---- S^T strip: rows = 64 keys (4 blocks), cols = wave's 16 q ----
    f32x4 sacc[4];
#pragma unroll
    for (int i = 0; i < 4; ++i) sacc[i] = (f32x4){0.f, 0.f, 0.f, 0.f};
#pragma unroll
    for (int s = 0; s < 2; ++s) {
      int qr = w * 16 + l16;
      bf16x8 qf = *(const bf16x8*)(sQ + qr * 128 + ((((s << 2) + lh) ^ (qr & 7)) << 4));
#pragma unroll
      for (int i = 0; i < 4; ++i) {
        int krr = i * 16 + l16;
        bf16x8 kf = *(const bf16x8*)(sK + krr * 128 + ((((s << 2) + lh) ^ (krr & 7)) << 4));
        sacc[i] = __builtin_amdgcn_mfma_f32_16x16x32_bf16(kf, qf, sacc[i], 0, 0, 0);
      }
    }

    // ---- softmax (lane owns one q) ----
    float sv[4][4];
    float tm = -1e30f;
#pragma unroll
    for (int i = 0; i < 4; ++i)
#pragma unroll
      for (int r = 0; r < 4; ++r) {
        float v = sacc[i][r] * 0.125f;
        if (k0 + i * 16 + lh * 4 + r >= DWT_) v = -1e30f;
        sv[i][r] = v;
        tm = fmaxf(tm, v);
      }
    tm = fmaxf(tm, __shfl_xor(tm, 16));
    tm = fmaxf(tm, __shfl_xor(tm, 32));
    float mn = fmaxf(m_, tm);
    float corr = __expf(m_ - mn);
    m_ = mn;
    float ts = 0.f;
    float p[4][4];
#pragma unroll
    for (int i = 0; i < 4; ++i)
#pragma unroll
      for (int r = 0; r < 4; ++r) {
        float e = __expf(sv[i][r] - mn);
        p[i][r] = e; ts += e;
      }
    ts += __shfl_xor(ts, 16);
    ts += __shfl_xor(ts, 32);
    l_ = l_ * corr + ts;

    // rescale accO (rows q-local = lh*4 + r; corr held by lane q-local)
#pragma unroll
    for (int r = 0; r < 4; ++r) {
      float cr = __shfl(corr, (lh << 2) + r);
#pragma unroll
      for (int jb = 0; jb < 4; ++jb) accO[jb][r] *= cr;
    }

    // gate + write P bf16 to wave-private LDS [q=l16][key]
#pragma unroll
    for (int i = 0; i < 4; ++i)
#pragma unroll
      for (int r = 0; r < 4; ++r) {
        float pv = p[i][r];
        int key = i * 16 + (lh << 2) + r;
        if (hg) pv *= sG[key];
        int slot = (key >> 3) ^ (l16 & 7);
        *(unsigned short*)(sPw + l16 * 128 + (slot << 4) + (key & 7) * 2) = f2bf(pv);
      }

    // ---- PV: A = P [16q][64key], B = V [key][d] from sV[d][key] ----
#pragma unroll
    for (int s = 0; s < 2; ++s) {
      bf16x8 pf = *(const bf16x8*)(sPw + l16 * 128 + ((((s << 2) + lh) ^ (l16 & 7)) << 4));
#pragma unroll
      for (int jb = 0; jb < 4; ++jb) {
        int vr = jb * 16 + l16;
        bf16x8 vf = *(const bf16x8*)(sV + vr * 128 + ((((s << 2) + lh) ^ (vr & 7)) << 4));
        accO[jb] = __builtin_amdgcn_mfma_f32_16x16x32_bf16(pf, vf, accO[jb], 0, 0, 0);
      }
    }
  }
#undef LOADT

  // ---- epilogue ----
  float linv = 1.f / l_;
#pragma unroll
  for (int r = 0; r < 4; ++r) {
    float li = __shfl(linv, (lh << 2) + r);
    int q = q0 + w * 16 + (lh << 2) + r;
    if (q >= DWT_) continue;
#pragma unroll
    for (int jb = 0; jb < 4; ++jb) {
      Oz[(size_t)(bD + q) * 512 + h64 + jb * 16 + l16] = f2bf(accO[jb][r] * li);
    }
  }
}

// ---------------------------------------------------------------------------
// fused LayerNorm, all residual inputs bf16 -> bf16 outputs (fp32 internal)
__global__ __launch_bounds__(256) void k_ln2(
    const unsigned short* __restrict__ llseq, const unsigned short* __restrict__ llout,
    const unsigned short* __restrict__ crossp,
    const unsigned short* __restrict__ lhseq, const unsigned short* __restrict__ lhout,
    const float* __restrict__ g, const float* __restrict__ beta,
    unsigned short* __restrict__ llf, unsigned short* __restrict__ lhf)
{
  __shared__ float red[256], red2[256];
  int row = blockIdx.x, tid = threadIdx.x, zz = blockIdx.y;
  const unsigned short* a  = zz ? lhseq : llseq;
  const unsigned short* b2 = zz ? lhout : llout;
  const unsigned short* c  = zz ? nullptr : crossp;
  const float* gg = g + zz * D_;
  const float* bb = beta + zz * D_;
  unsigned short* outp = zz ? lhf : llf;
  size_t base = (size_t)row * D_ + 2 * tid;
  unsigned av = *(const unsigned*)(a + base);
  unsigned bv = *(const unsigned*)(b2 + base);
  float v0 = bf2f((unsigned short)av) + bf2f((unsigned short)bv);
  float v1 = bf2f((unsigned short)(av >> 16)) + bf2f((unsigned short)(bv >> 16));
  if (c) {
    unsigned cv = *(const unsigned*)(c + base);
    v0 += bf2f((unsigned short)cv);
    v1 += bf2f((unsigned short)(cv >> 16));
  }
  red[tid] = v0 + v1; red2[tid] = v0 * v0 + v1 * v1;
  __syncthreads();
  for (int o = 128; o > 0; o >>= 1) {
    if (tid < o) { red[tid] += red[tid + o]; red2[tid] += red2[tid + o]; }
    __syncthreads();
  }
  float mu = red[0] / (float)D_;
  float var = red2[0] / (float)D_ - mu * mu;
  float rstd = rsqrtf(var + 1e-5f);
  float y0 = (v0 - mu) * rstd * gg[2 * tid] + bb[2 * tid];
  float y1 = (v1 - mu) * rstd * gg[2 * tid + 1] + bb[2 * tid + 1];
  *(unsigned*)(outp + base) = (unsigned)f2bf(y0) | ((unsigned)f2bf(y1) << 16);
}

// ---------------------------------------------------------------------------
// merged: blocks 0..1021 head_partial (head_W chunk staged through LDS, each
// byte fetched once; 192 compute threads own full (b, 4-pred) outputs);
// 1022..1533 recon with coalesced 16-o-chunk writes.
__global__ __launch_bounds__(512) void k_headrec(
    const float* __restrict__ llo, const float* __restrict__ lho,
    const float* __restrict__ llg, const float* __restrict__ lhg,
    const float* __restrict__ hw, float* __restrict__ part,
    const float* __restrict__ h, const float* __restrict__ g,
    float* __restrict__ outp)
{
  __shared__ float lds[8][520];   // +8 pad: 8 pb-broadcast rows spread banks
  __shared__ float sW[6144];      // 64 k-rows x 96 preds (24KB chunk)
  int bid = blockIdx.x, tid = threadIdx.x;
  if (bid < 2 * DWT_) {
    int x = bid;
    int branch = x / DWT_, t = x % DWT_;
    const float* seq = branch ? lho : llo;
    const float* gt  = branch ? lhg : llg;
    for (int i = tid; i < 4096; i += 512) {
      int b = i >> 9, d = i & 511;
      lds[b][d] = seq[((size_t)b * DWT_ + t) * D_ + d] * gt[(size_t)t * D_ + d];
    }
    const bool act = tid < 192;
    const int pb_ = tid / 24, j = tid % 24;   // b 0..7, pred-quad 0..23
    f32x4 acc = (f32x4){0.f, 0.f, 0.f, 0.f};
    const float* hwx = hw + (size_t)x * (D_ * 96);
    for (int c = 0; c < 8; ++c) {
      __syncthreads();
      // cooperative stage of 64 k-rows (6144 floats), perfectly coalesced
      {
        const float* src = hwx + (size_t)c * 6144 + tid * 12;
        float4 v0 = *(const float4*)(src);
        float4 v1 = *(const float4*)(src + 4);
        float4 v2 = *(const float4*)(src + 8);
        *(float4*)&sW[tid * 12]     = v0;
        *(float4*)&sW[tid * 12 + 4] = v1;
        *(float4*)&sW[tid * 12 + 8] = v2;
      }
      __syncthreads();
      if (act) {
        int k0 = c * 64;
#pragma unroll 8
        for (int k = 0; k < 64; ++k) {
          float s = lds[pb_][k0 + k];
          float4 wv = *(const float4*)&sW[k * 96 + j * 4];
          acc[0] += s * wv.x; acc[1] += s * wv.y;
          acc[2] += s * wv.z; acc[3] += s * wv.w;
        }
      }
    }
    if (act)
      *(f32x4*)&part[(size_t)x * 768 + pb_ * 96 + j * 4] = acc;
  } else {
    int rid = bid - 2 * DWT_;
    int b = rid >> 6, ot = rid & 63;
    int o0 = ot << 4;
    int d = tid;
    float h4[4], g4[4];
#pragma unroll
    for (int k = 0; k < 4; ++k) { h4[k] = h[d * 4 + k]; g4[k] = g[d * 4 + k]; }
    int tb = (o0 >> 1) - 1;
    float rl[10], rh[10];
#pragma unroll
    for (int k = 0; k < 10; ++k) {
      int t = tb + k;
      bool ok = (t >= 0 && t < DWT_);
      size_t ix = ((size_t)(b * DWT_ + (ok ? t : 0))) * D_ + d;
      rl[k] = ok ? llo[ix] : 0.f;
      rh[k] = ok ? lho[ix] : 0.f;
    }
    float* ob = outp + ((size_t)(b * D_ + d)) * RECON_LEN + o0;
#pragma unroll
    for (int j2 = 0; j2 < 16; ++j2) {
      int o = o0 + j2;
      float acc;
      if ((j2 & 1) == 0) {
        int ix = (j2 >> 1) + 1;
        acc = rl[ix - 1] * h4[3] + rh[ix - 1] * g4[3] + rl[ix] * h4[1] + rh[ix] * g4[1];
      } else {
        int ix = ((j2 - 1) >> 1) + 1;
        acc = rl[ix] * h4[2] + rh[ix] * g4[2] + rl[ix + 1] * h4[0] + rh[ix + 1] * g4[0];
      }
      if (o < RECON_LEN) ob[j2] = acc;
    }
  }
}

// block = b; lane = pred (coalesced part reads); 4 c-groups + LDS combine
__global__ __launch_bounds__(512) void k_head_final(const float* __restrict__ part,
    const float* __restrict__ hb, const float* __restrict__ rw,
    const float* __restrict__ rb, const float* __restrict__ meanp,
    const float* __restrict__ stdp, float* __restrict__ preds)
{
  __shared__ float red[4][96];
  int b = blockIdx.x;
  int p = threadIdx.x & 127, cg = threadIdx.x >> 7;
  if (p < 96) {
    float s = 0.f;
    for (int c = cg; c < 2 * DWT_; c += 4)
      s += part[(size_t)c * 768 + b * 96 + p];
    red[cg][p] = s;
  }
  __syncthreads();
  if (cg == 0 && p < 96) {
    float acc = red[0][p] + red[1][p] + red[2][p] + red[3][p] + hb[p];
    preds[b * 96 + p] = (acc - rb[0]) / (rw[0] + 1e-10f) * stdp[b] + meanp[b];
  }
}

// ---------------------------------------------------------------------------
extern "C" void kernel_launch(void* const* d_in, const int* in_sizes, int n_in,
                              void* d_out, int out_size, void* d_ws, size_t ws_size,
                              hipStream_t stream)
{
  const float* x       = (const float*)d_in[0];
  const float* revin_w = (const float*)d_in[1];
  const float* revin_b = (const float*)d_in[2];
  const float* patch_W = (const float*)d_in[3];
  const float* patch_b = (const float*)d_in[4];
  const float* pos_emb = (const float*)d_in[5];
  const float* dwt_h   = (const float*)d_in[6];
  const float* dwt_g   = (const float*)d_in[7];
  const float* raw_tau = (const float*)d_in[8];
  const float* attn_W  = (const float*)d_in[9];
  const float* attn_b  = (const float*)d_in[10];
  const float* mlp_W1  = (const float*)d_in[11];
  const float* mlp_b1  = (const float*)d_in[12];
  const float* mlp_W2  = (const float*)d_in[13];
  const float* mlp_b2  = (const float*)d_in[14];
  const float* ln_g    = (const float*)d_in[15];
  const float* ln_b    = (const float*)d_in[16];
  const float* ll_gate = (const float*)d_in[17];
  const float* lh_gate = (const float*)d_in[18];
  const float* head_W  = (const float*)d_in[19];
  const float* head_b  = (const float*)d_in[20];

  float* ws  = (float*)d_ws;
  float* out = (float*)d_out;

  float* meanp = ws + WS_MEAN;
  float* stdp  = ws + WS_STD;
  float* xn    = ws + WS_XN;
  float* pseq  = ws + WS_PSEQ;
  float* gateb = ws + WS_GATE;
  float* llo   = ws + WS_LLO;
  float* lho   = ws + WS_LHO;
  float* part  = ws + WS_PART;

  unsigned short* llseq16 = (unsigned short*)(ws + WS_LLSEQ);
  unsigned short* lhseq16 = (unsigned short*)(ws + WS_LHSEQ);
  unsigned short* cross16 = (unsigned short*)(ws + WS_CROSS);
  unsigned short* llf16 = (unsigned short*)(ws + WS_LLF);
  unsigned short* lhf16 = (unsigned short*)(ws + WS_LHF);
  unsigned short* Qb16  = (unsigned short*)(ws + WS_QB);
  unsigned short* Kb16  = (unsigned short*)(ws + WS_KB);
  unsigned short* Vt16  = (unsigned short*)(ws + WS_VT);
  unsigned short* Ob16  = (unsigned short*)(ws + WS_OB);
  unsigned short* hid16 = (unsigned short*)(ws + WS_HID2);
  unsigned short* llout16 = (unsigned short*)(ws + WS_LLO16);
  unsigned short* lhout16 = llout16 + 2093056;

  unsigned short* wt  = (unsigned short*)(ws + WS_WT);    // bf16 weights (own region)
  unsigned short* w1t = wt + 12 * 262144;                 // 2 x [2048][512]
  unsigned short* w2t = w1t + 2 * 1048576;                // 2 x [512][2048]

  // ---- stage 0: RevIN + (patch|weight-prep) + (transpose|DWT+gate) ----
  k_revin<<<8, 256, 0, stream>>>(x, revin_w, revin_b, meanp, stdp, xn);
  k_pw<<<8184 + 7168, 512, 0, stream>>>(xn, patch_W, patch_b, pos_emb, pseq,
                                        attn_W, mlp_W1, mlp_W2, wt, w1t, w2t);
  k_td<<<4096 + 256, 512, 0, stream>>>(pseq, out + PATCHES_O, dwt_h, dwt_g,
                                       llseq16, lhseq16, out + OUT_LL_O,
                                       out + OUT_LH_O, raw_tau, gateb);

  // ---- stage 1: LL + LH MHAs batched ----
  k_gemm_mfma<64,3><<<dim3(12, 64, 2), 256, 0, stream>>>(
      llseq16, llseq16, lhseq16, lhseq16, wt, attn_b, nullptr, nullptr,
      Qb16, Kb16, Vt16, MR_, 1536, D_, 0, 4 * 262144, 2048);
  k_mattn<<<dim3(64, 8, 2), 256, 0, stream>>>(Qb16, Kb16, Vt16, gateb, Ob16);
  k_gemm_mfma<64,1><<<dim3(4, 64, 2), 256, 0, stream>>>(
      Ob16, nullptr, Ob16 + (size_t)2093056, nullptr, wt + 3 * 262144,
      attn_b + 1536, nullptr, nullptr, llout16, lhout16, nullptr,
      MR_, D_, D_, 0, 4 * 262144, 2048);

  // ---- cross MHA: Q from llout16, K/V from lhout16 ----
  k_gemm_mfma<64,3><<<dim3(12, 64, 1), 256, 0, stream>>>(
      llout16, lhout16, nullptr, nullptr, wt + 8 * 262144, attn_b + 2 * 2048,
      nullptr, nullptr, Qb16, Kb16, Vt16, MR_, 1536, D_, 0, 0, 0);
  k_mattn<<<dim3(64, 8, 1), 256, 0, stream>>>(Qb16, Kb16, Vt16, nullptr, Ob16);
  k_gemm_mfma<64,1><<<dim3(4, 64, 1), 256, 0, stream>>>(
      Ob16, nullptr, nullptr, nullptr, wt + 11 * 262144, attn_b + 2 * 2048 + 1536,
      nullptr, nullptr, cross16, nullptr, nullptr, MR_, D_, D_, 0, 0, 0);

  // ---- stage 2: fused LN (bf16) + batched MLP ----
  k_ln2<<<dim3(MR_, 2), 256, 0, stream>>>(llseq16, llout16, cross16,
                                          lhseq16, lhout16, ln_g, ln_b,
                                          llf16, lhf16);
  k_gemm_mfma<128,1><<<dim3(16, 32, 2), 256, 0, stream>>>(
      llf16, nullptr, lhf16, nullptr, w1t, mlp_b1, nullptr, nullptr,
      hid16, hid16 + (size_t)4088 * 2048, nullptr, MR_, DFF_, D_, 1,
      1048576, 2048);
  k_gemm_mfma<64,0,1><<<dim3(4, 64, 2), 256, 0, stream>>>(
      hid16, nullptr, hid16 + (size_t)4088 * 2048, nullptr, w2t, mlp_b2,
      llf16, lhf16, llo, lho, nullptr, MR_, D_, DFF_, 0, 1048576, 512);

  // ---- stage 3: (head_partial | recon) merged + head_final ----
  k_headrec<<<2 * DWT_ + 512, 512, 0, stream>>>(llo, lho, ll_gate, lh_gate,
                                                head_W, part, dwt_h, dwt_g,
                                                out + RECON_O);
  k_head_final<<<8, 512, 0, stream>>>(part, head_b, revin_w, revin_b, meanp, stdp,
                                      out + PREDS_O);
}

// Round 15
// 398.319 us; speedup vs baseline: 1.1504x; 1.1504x over previous
//
#include <hip/hip_runtime.h>
#include <math.h>

#define B_    8
#define SEQ_  8192
#define D_    512
#define N_    1023
#define DWT_  511
#define DFF_  2048
#define MR_   (B_ * DWT_)          // 4088 rows for all [B*L, D] GEMMs

// ---------------- d_out layout (flat concat of the 5 outputs) ----------------
#define PREDS_O    0
#define RECON_O    768
#define RECON_LEN  1022
#define PATCHES_O  (RECON_O + 8*512*1022)   // 4186880
#define OUT_LL_O   (PATCHES_O + 8*512*1023) // 8377088
#define OUT_LH_O   (OUT_LL_O + 8*512*511)   // 10470144

// ---------------- workspace layout (float units) ----------------
#define WS_MEAN   ((size_t)0)
#define WS_STD    ((size_t)8)
#define WS_XN     ((size_t)16)
#define WS_PSEQ   ((size_t)65552)
#define WS_LLSEQ  ((size_t)4255760)    // bf16 [4088][512]
#define WS_LHSEQ  ((size_t)6348816)    // bf16
#define WS_CROSS  ((size_t)21000208)   // bf16 [4088][512] (cross16)
#define WS_GATE   ((size_t)23093264)
#define WS_LLF    ((size_t)23097352)   // bf16 [4088][512]
#define WS_LHF    ((size_t)25190408)   // bf16
#define WS_LLO    ((size_t)16814096)   // fp32 [4088][512] (MLP out, LL)
#define WS_LHO    ((size_t)18907152)   // fp32 (LH)
#define WS_PART   WS_CROSS             // head partials alias cross (disjoint phase)
// bf16 buffers beyond the old arena (ws ~766MiB)
#define WS_QB     ((size_t)27283464)   // 2 x [4088][512] bf16
#define WS_KB     (WS_QB + 2093056)
#define WS_VT     (WS_KB + 2093056)    // 2 x [4096][512] bf16
#define WS_OB     (WS_VT + 2097152)
#define WS_HID2   (WS_OB + 2093056)    // 2 x [4088][2048] bf16
#define WS_LLO16  (WS_HID2 + 8372224)  // 2 x [4088][512] bf16 (llout16, lhout16)
#define WS_WT     ((size_t)48218120)   // bf16 weight arena (own region, no alias!)

using bf16x8 = __attribute__((ext_vector_type(8))) short;
using u16x8  = __attribute__((ext_vector_type(8))) unsigned short;
using f32x4  = __attribute__((ext_vector_type(4))) float;

__device__ inline unsigned short f2bf(float f) {
  unsigned u = __float_as_uint(f);
  u += 0x7fffu + ((u >> 16) & 1u);    // round-to-nearest-even
  return (unsigned short)(u >> 16);
}
__device__ inline float bf2f(unsigned short h) {
  return __uint_as_float(((unsigned)h) << 16);
}

// async global->LDS DMA, 16B per lane; lds base must be wave-uniform.
__device__ __forceinline__ void gld16(const void* g, void* lds) {
  __builtin_amdgcn_global_load_lds(
      (const __attribute__((address_space(1))) unsigned int*)g,
      (__attribute__((address_space(3))) unsigned int*)lds, 16, 0, 0);
}

// ---------------------------------------------------------------------------
__global__ __launch_bounds__(256) void k_revin(const float* __restrict__ x,
    const float* __restrict__ rw, const float* __restrict__ rb,
    float* __restrict__ meanp, float* __restrict__ stdp, float* __restrict__ xn)
{
  __shared__ float rs[256], rs2[256];
  int b = blockIdx.x, tid = threadIdx.x;
  const float* xb = x + (size_t)b * SEQ_;
  float s = 0.f, s2 = 0.f;
  for (int i = tid; i < SEQ_; i += 256) { float v = xb[i]; s += v; s2 += v * v; }
  rs[tid] = s; rs2[tid] = s2; __syncthreads();
  for (int o = 128; o > 0; o >>= 1) {
    if (tid < o) { rs[tid] += rs[tid + o]; rs2[tid] += rs2[tid + o]; }
    __syncthreads();
  }
  float mu = rs[0] / SEQ_;
  float var = rs2[0] / SEQ_ - mu * mu;
  float sd = sqrtf(var + 1e-5f);
  if (tid == 0) { meanp[b] = mu; stdp[b] = sd; }
  float w = rw[0], bb = rb[0], inv = 1.f / sd;
  for (int i = tid; i < SEQ_; i += 256)
    xn[(size_t)b * SEQ_ + i] = (xb[i] - mu) * inv * w + bb;
}

// ---------------------------------------------------------------------------
// merged: blocks 0..8183 patch-embed; 8184..15351 weight transpose+convert.
__global__ __launch_bounds__(512) void k_pw(const float* __restrict__ xn,
    const float* __restrict__ pW, const float* __restrict__ pb,
    const float* __restrict__ pos, float* __restrict__ p_seq,
    const float* __restrict__ attn_W, const float* __restrict__ mlp_W1,
    const float* __restrict__ mlp_W2, unsigned short* __restrict__ wt,
    unsigned short* __restrict__ w1t, unsigned short* __restrict__ w2t)
{
  __shared__ float sx[16];
  __shared__ float tl[32][33];
  int bid = blockIdx.x, tid = threadIdx.x;
  if (bid < 8184) {
    int n = bid % N_, b = bid / N_, d = tid;
    if (tid < 16) sx[tid] = xn[(size_t)b * SEQ_ + n * 8 + tid];
    __syncthreads();
    float acc = pb[d] + pos[(size_t)n * D_ + d];
#pragma unroll
    for (int k = 0; k < 16; ++k) acc += sx[k] * pW[k * D_ + d];
    p_seq[((size_t)b * N_ + n) * D_ + d] = acc;
  } else {
    int b2 = bid - 8184;
    const float* src; unsigned short* dst; int K, N, nx, ky;
    if (b2 < 3072) {
      int z = b2 >> 8, r = b2 & 255;
      nx = r & 15; ky = r >> 4; K = 512; N = 512;
      src = attn_W + (size_t)z * 262144; dst = wt + (size_t)z * 262144;
    } else if (b2 < 5120) {
      int b3 = b2 - 3072; int z = b3 >> 10, r = b3 & 1023;
      nx = r & 63; ky = r >> 6; K = 512; N = 2048;
      src = mlp_W1 + (size_t)z * 1048576; dst = w1t + (size_t)z * 1048576;
    } else {
      int b4 = b2 - 5120; int z = b4 >> 10, r = b4 & 1023;
      nx = r & 15; ky = r >> 4; K = 2048; N = 512;
      src = mlp_W2 + (size_t)z * 1048576; dst = w2t + (size_t)z * 1048576;
    }
    int n0 = nx * 32, k0 = ky * 32;
    int tx = tid & 31, ty = tid >> 5;    // ty 0..15
#pragma unroll
    for (int r = 0; r < 2; ++r)
      tl[ty + 16 * r][tx] = src[(size_t)(k0 + ty + 16 * r) * N + n0 + tx];
    __syncthreads();
#pragma unroll
    for (int r = 0; r < 2; ++r)
      dst[(size_t)(n0 + ty + 16 * r) * K + k0 + tx] = f2bf(tl[tx][ty + 16 * r]);
  }
}

// ---------------------------------------------------------------------------
// merged: blocks 0..4095 transpose pseq -> patches; 4096..4351 DWT+gate with
// coalesced [d][t]-chunk writes (16 consecutive t per thread = 64B/lane).
__global__ __launch_bounds__(512) void k_td(const float* __restrict__ p_seq,
    float* __restrict__ patches, const float* __restrict__ h,
    const float* __restrict__ g, unsigned short* __restrict__ ll_seq,
    unsigned short* __restrict__ lh_seq, float* __restrict__ ll_out,
    float* __restrict__ lh_out, const float* __restrict__ raw_tau,
    float* __restrict__ gate)
{
  __shared__ float tile[32][33];
  __shared__ float gpart[16][8];
  int bid = blockIdx.x, tid = threadIdx.x;
  if (bid < 4096) {
    int d0 = (bid & 15) * 32, n0 = ((bid >> 4) & 31) * 32, b = bid >> 9;
    int tx = tid & 31, ty = tid >> 5;   // ty 0..15
#pragma unroll
    for (int r = 0; r < 2; ++r) {
      int n = n0 + ty + 16 * r;
      if (n < N_) tile[ty + 16 * r][tx] = p_seq[((size_t)b * N_ + n) * D_ + d0 + tx];
    }
    __syncthreads();
#pragma unroll
    for (int r = 0; r < 2; ++r) {
      int d = d0 + ty + 16 * r, n = n0 + tx;
      if (n < N_) patches[((size_t)b * D_ + d) * N_ + n] = tile[tx][ty + 16 * r];
    }
  } else {
    int idx = bid - 4096;               // 0..255
    int b = idx >> 5, tt = idx & 31;
    int t0 = tt << 4;
    int d = tid;
    float h4[4], g4[4];
#pragma unroll
    for (int k = 0; k < 4; ++k) { h4[k] = h[d * 4 + k]; g4[k] = g[d * 4 + k]; }
    float llv[16], lhv[16], av[16];
#pragma unroll
    for (int i = 0; i < 16; ++i) {
      int t = t0 + i;
      float ah = 0.f, ag = 0.f;
      if (t < DWT_) {
#pragma unroll
        for (int k = 0; k < 4; ++k) {
          int n = 2 * t + k - 1;
          if (n >= 0 && n < N_) {
            float v = p_seq[((size_t)b * N_ + n) * D_ + d];
            ah += v * h4[k]; ag += v * g4[k];
          }
        }
      }
      llv[i] = ah; lhv[i] = ag; av[i] = fabsf(ag);
    }
    // bf16 sequence writes ([t][d]-major, coalesced)
#pragma unroll
    for (int i = 0; i < 16; ++i) {
      int t = t0 + i;
      if (t < DWT_) {
        ll_seq[((size_t)b * DWT_ + t) * D_ + d] = f2bf(llv[i]);
        lh_seq[((size_t)b * DWT_ + t) * D_ + d] = f2bf(lhv[i]);
      }
    }
    // fp32 d_out writes: 16 consecutive t per thread = one 64B line per lane
    size_t ob = ((size_t)b * D_ + d) * DWT_ + t0;
#pragma unroll
    for (int i = 0; i < 16; ++i) {
      if (t0 + i < DWT_) { ll_out[ob + i] = llv[i]; lh_out[ob + i] = lhv[i]; }
    }
    // gate: butterfly-reduce each of 16 t's across the wave, then LDS combine
#pragma unroll
    for (int off = 1; off < 64; off <<= 1)
#pragma unroll
      for (int i = 0; i < 16; ++i) av[i] += __shfl_xor(av[i], off);
    int lane = tid & 63, w = tid >> 6;
    if (lane == 0) {
#pragma unroll
      for (int i = 0; i < 16; ++i) gpart[i][w] = av[i];
    }
    __syncthreads();
    if (tid < 16) {
      float s = 0.f;
#pragma unroll
      for (int w2 = 0; w2 < 8; ++w2) s += gpart[tid][w2];
      int t = t0 + tid;
      if (t < DWT_) {
        float tau = 1.f / (1.f + expf(-raw_tau[0]));
        float e = s / (float)D_;
        gate[(size_t)b * DWT_ + t] = 1.f / (1.f + expf(-(e - tau) * 10.f));
      }
    }
  }
}

// ---------------------------------------------------------------------------
// C = A(bf16) @ WT(bf16 [N][K])^T + bias (+res) (opt gelu) via MFMA, z-batched.
// 2-phase double-buffered K-loop with counted vmcnt (DMA stays in flight).
// CMODE 0: fp32 C[m][n] (+res; RESBF: residual bf16). 1: bf16 C[m][n].
// CMODE 3: fused QKV: n<512->Q bf16; <1024->K bf16; >=1024->V transposed.
template<int BM, int CMODE, int RESBF = 0>
__global__ __launch_bounds__(256, BM == 64 ? 3 : 2) void k_gemm_mfma(
    const void* __restrict__ A00, const void* __restrict__ A01,
    const void* __restrict__ A10, const void* __restrict__ A11,
    const unsigned short* __restrict__ WT, const float* __restrict__ bias,
    const void* __restrict__ res0, const void* __restrict__ res1,
    void* __restrict__ C0, void* __restrict__ C1, void* __restrict__ C2,
    int M, int N, int K, int act, int zsW, int zsB)
{
  __shared__ unsigned char lds[2][(BM + 128) * 128];

  const int tid = threadIdx.x;
  const int wid = tid >> 6, lane = tid & 63;
  const int n0 = blockIdx.x * 128, m0 = blockIdx.y * BM;
  const int z = blockIdx.z;
  constexpr int MI = 4;
  constexpr int NI = (BM == 128) ? 4 : 2;
  const int wrow = (BM == 128) ? (wid >> 1) * 64 : 0;
  const int wcol = (BM == 128) ? (wid & 1) * 64 : wid * 32;
  const int l16 = lane & 15, lh = lane >> 4;

  const unsigned short* wt_ = WT + (size_t)z * zsW;
  const float* bias_ = bias + (size_t)z * zsB;
  const unsigned short* Ap;
  if (CMODE == 3) Ap = (const unsigned short*)(z ? (n0 < 512 ? A10 : A11)
                                                 : (n0 < 512 ? A00 : A01));
  else            Ap = (const unsigned short*)(z ? A10 : A00);

  f32x4 acc[MI][NI];
#pragma unroll
  for (int i = 0; i < MI; ++i)
#pragma unroll
    for (int j = 0; j < NI; ++j) acc[i][j] = (f32x4){0.f, 0.f, 0.f, 0.f};

  const int nk = K >> 6;
  auto stage = [&](int t, int buf) {
    unsigned char* sA = lds[buf];
    unsigned char* sB = lds[buf] + BM * 128;
    int k0 = t << 6;
    constexpr int PA = BM / 32;
#pragma unroll
    for (int p = 0; p < PA; ++p) {
      int s0 = wid * (BM * 2) + p * 64;
      int s = s0 + lane;
      int row = s >> 3, oct = s & 7;
      int gr = m0 + row; if (gr > M - 1) gr = M - 1;
      gld16(Ap + (size_t)gr * K + k0 + ((oct ^ (row & 7)) << 3),
            sA + (size_t)s0 * 16);
    }
#pragma unroll
    for (int p = 0; p < 4; ++p) {
      int s0 = wid * 256 + p * 64;
      int s = s0 + lane;
      int row = s >> 3, oct = s & 7;
      gld16(wt_ + (size_t)(n0 + row) * K + k0 + ((oct ^ (row & 7)) << 3),
            sB + (size_t)s0 * 16);
    }
  };

  stage(0, 0);
  for (int t = 0; t < nk; ++t) {
    const int cur = t & 1;
    if (t + 1 < nk) {
      stage(t + 1, cur ^ 1);
      if constexpr (BM == 64) asm volatile("s_waitcnt vmcnt(6)" ::: "memory");
      else                    asm volatile("s_waitcnt vmcnt(8)" ::: "memory");
    } else {
      asm volatile("s_waitcnt vmcnt(0)" ::: "memory");
    }
    __builtin_amdgcn_sched_barrier(0);
    __builtin_amdgcn_s_barrier();
    __builtin_amdgcn_sched_barrier(0);
    unsigned char* sA = lds[cur];
    unsigned char* sB = lds[cur] + BM * 128;
#pragma unroll
    for (int s = 0; s < 2; ++s) {
      bf16x8 af[MI], bfr[NI];
#pragma unroll
      for (int i = 0; i < MI; ++i) {
        int r = wrow + i * 16 + l16;
        af[i] = *(const bf16x8*)(sA + r * 128 + (((s * 4 + lh) ^ (r & 7)) << 4));
      }
#pragma unroll
      for (int j = 0; j < NI; ++j) {
        int r = wcol + j * 16 + l16;
        bfr[j] = *(const bf16x8*)(sB + r * 128 + (((s * 4 + lh) ^ (r & 7)) << 4));
      }
#pragma unroll
      for (int i = 0; i < MI; ++i)
#pragma unroll
        for (int j = 0; j < NI; ++j)
          acc[i][j] = __builtin_amdgcn_mfma_f32_16x16x32_bf16(af[i], bfr[j],
                                                              acc[i][j], 0, 0, 0);
    }
    __builtin_amdgcn_sched_barrier(0);
    __builtin_amdgcn_s_barrier();
  }
  // ---- epilogue ----
  const void* res_ = z ? res1 : res0;
#pragma unroll
  for (int i = 0; i < MI; ++i) {
#pragma unroll
    for (int r = 0; r < 4; ++r) {
      int m = m0 + wrow + i * 16 + lh * 4 + r;
      if (m >= M) continue;
#pragma unroll
      for (int j = 0; j < NI; ++j) {
        int n = n0 + wcol + j * 16 + l16;
        float v = acc[i][j][r] + bias_[n];
        if (act) v = 0.5f * v * (1.f + erff(v * 0.70710678118654752f));
        if (CMODE == 0) {
          float* Cp = (float*)(z ? C1 : C0);
          if (res_) {
            float rv = RESBF ? bf2f(((const unsigned short*)res_)[(size_t)m * N + n])
                             : ((const float*)res_)[(size_t)m * N + n];
            v += rv;
          }
          Cp[(size_t)m * N + n] = v;
        } else if (CMODE == 1) {
          unsigned short* Cp = (unsigned short*)(z ? C1 : C0);
          Cp[(size_t)m * N + n] = f2bf(v);
        } else {
          if (n < 512) {
            ((unsigned short*)C0)[(size_t)z * 2093056 + (size_t)m * 512 + n] = f2bf(v);
          } else if (n < 1024) {
            ((unsigned short*)C1)[(size_t)z * 2093056 + (size_t)m * 512 + (n - 512)] = f2bf(v);
          } else {
            int bb = m / DWT_;
            int key = m - bb * DWT_;
            ((unsigned short*)C2)[(size_t)z * 2097152 +
                ((size_t)(bb * 512 + (n - 1024))) * 512 + key] = f2bf(v);
          }
        }
      }
    }
  }
}

// ---------------------------------------------------------------------------
// MFMA flash attention, z-batched, register-prefetched K/V staging (T14).
__global__ __launch_bounds__(256) void k_mattn(
    const unsigned short* __restrict__ Qb, const unsigned short* __restrict__ Kb,
    const unsigned short* __restrict__ Vt, const float* __restrict__ gate,
    unsigned short* __restrict__ Ob)
{
  __shared__ unsigned char sQ[8192], sK[8192], sV[8192], sP[8192];
  __shared__ float sG[64];

  const int bh = blockIdx.x;
  const int b = bh >> 3;
  const int q0 = blockIdx.y * 64;
  const int z = blockIdx.z;
  const int tid = threadIdx.x;
  const int w = tid >> 6, lane = tid & 63;
  const int l16 = lane & 15, lh = lane >> 4;
  const bool hg = (z == 1) && (gate != nullptr);
  const int bD = b * DWT_;

  const unsigned short* Qz = Qb + (size_t)z * 2093056;
  const unsigned short* Kz = Kb + (size_t)z * 2093056;
  const unsigned short* Vz = Vt + (size_t)z * 2097152;
  unsigned short* Oz = Ob + (size_t)z * 2093056;
  const int h64 = (bh & 7) * 64;
  const unsigned short* vrow = Vz + (size_t)bh * 64 * 512;

  // stage Q tile [64 q][64 d]
#pragma unroll
  for (int it = 0; it < 2; ++it) {
    int i = it * 256 + tid;
    int row = i >> 3, oct = i & 7;
    int qr = q0 + row; if (qr > DWT_ - 1) qr = DWT_ - 1;
    u16x8 v = *(const u16x8*)(Qz + (size_t)(bD + qr) * 512 + h64 + oct * 8);
    *(u16x8*)(sQ + row * 128 + ((oct ^ (row & 7)) << 4)) = v;
  }

  // preload full gate vector (2 keys per thread)
  float ga = 0.f, gb2 = 0.f;
  if (hg) {
    int k = 2 * tid;
    ga  = (k     < DWT_) ? gate[(size_t)bD + k]     : 0.f;
    gb2 = (k + 1 < DWT_) ? gate[(size_t)bD + k + 1] : 0.f;
  }

  float m_ = -1e30f, l_ = 0.f;
  f32x4 accO[4];
#pragma unroll
  for (int jb = 0; jb < 4; ++jb) accO[jb] = (f32x4){0.f, 0.f, 0.f, 0.f};

  unsigned char* sPw = sP + w * 2048;   // wave-private [16 q][64 key] bf16

  uint4 pk0, pk1, pv0, pv1;
#define LOADT(kt_) do {                                                      \
    int k0_ = (kt_) * 64;                                                    \
    int row_ = tid >> 3, oct_ = tid & 7;                                     \
    int kr0_ = k0_ + row_;      if (kr0_ > DWT_ - 1) kr0_ = DWT_ - 1;        \
    int kr1_ = k0_ + row_ + 32; if (kr1_ > DWT_ - 1) kr1_ = DWT_ - 1;        \
    pk0 = *(const uint4*)(Kz + (size_t)(bD + kr0_) * 512 + h64 + oct_ * 8);  \
    pk1 = *(const uint4*)(Kz + (size_t)(bD + kr1_) * 512 + h64 + oct_ * 8);  \
    pv0 = *(const uint4*)(vrow + (size_t)row_ * 512 + k0_ + oct_ * 8);       \
    pv1 = *(const uint4*)(vrow + (size_t)(row_ + 32) * 512 + k0_ + oct_ * 8);\
  } while (0)

  LOADT(0);
  for (int kt = 0; kt < 8; ++kt) {
    const int k0 = kt * 64;
    __syncthreads();                    // prior-iter PV reads complete
    {
      int row = tid >> 3, oct = tid & 7, row1 = (tid >> 3) + 32;
      *(uint4*)(sK + row  * 128 + ((oct ^ (row  & 7)) << 4)) = pk0;
      *(uint4*)(sK + row1 * 128 + ((oct ^ (row1 & 7)) << 4)) = pk1;
      *(uint4*)(sV + row  * 128 + ((oct ^ (row  & 7)) << 4)) = pv0;
      *(uint4*)(sV + row1 * 128 + ((oct ^ (row1 & 7)) << 4)) = pv1;
    }
    if (hg && (tid >> 5) == kt) {
      sG[(tid & 31) * 2]     = ga;
      sG[(tid & 31) * 2 + 1] = gb2;
    }
    __syncthreads();
    if (kt < 7) LOADT(kt + 1);          // prefetch next tile under compute

    // ---- S^T strip: rows = 64 keys (4 blocks), cols = wave's 16 q ----
    f32x4 sacc[4];
#pragma unroll
    for (int i = 0; i < 4; ++i) sacc[i] = (f32x4){0.f, 0.f, 0.f, 0.f};
#pragma unroll
    for (int s = 0; s < 2; ++s) {
      int qr = w * 16 + l16;
      bf16x8 qf = *(const bf16x8*)(sQ + qr * 128 + ((((s << 2) + lh) ^ (qr & 7)) << 4));
#pragma unroll
      for (int i = 0; i < 4; ++i) {
        int krr = i * 16 + l16;
        bf16x8 kf = *(const bf16x8*)(sK + krr * 128 + ((((s << 2) + lh) ^ (krr & 7)) << 4));
        sacc[i] = __builtin_amdgcn_mfma_f32_16x16x32_bf16(kf, qf, sacc[i], 0, 0, 0);
      }
    }

    // ---- softmax (lane owns one q) ----
    float sv[4][4];
    float tm = -1e30f;
#pragma unroll
    for (int i = 0; i < 4; ++i)
#pragma unroll
      for (int r = 0; r < 4; ++r) {
        float v = sacc[i][r] * 0.125f;
        if (k0 + i * 16 + lh * 4 + r >= DWT_) v = -1e30f;
        sv[i][r] = v;
        tm = fmaxf(tm, v);
      }
    tm = fmaxf(tm, __shfl_xor(tm, 16));
    tm = fmaxf(tm, __shfl_xor(tm, 32));
    float mn = fmaxf(m_, tm);
    float corr = __expf(m_ - mn);
    m_ = mn;
    float ts = 0.f;
    float p[4][4];
#pragma unroll
    for (int i = 0; i < 4; ++i)
#pragma unroll
      for (int r = 0; r < 4; ++r) {
        float e = __expf(sv[i][r] - mn);
        p[i][r] = e; ts += e;
      }
    ts += __shfl_xor(ts, 16);
    ts += __shfl_xor(ts, 32);
    l_ = l_ * corr + ts;

    // rescale accO (rows q-local = lh*4 + r; corr held by lane q-local)
#pragma unroll
    for (int r = 0; r < 4; ++r) {
      float cr = __shfl(corr, (lh << 2) + r);
#pragma unroll
      for (int jb = 0; jb < 4; ++jb) accO[jb][r] *= cr;
    }

    // gate + write P bf16 to wave-private LDS [q=l16][key]
#pragma unroll
    for (int i = 0; i < 4; ++i)
#pragma unroll
      for (int r = 0; r < 4; ++r) {
        float pv = p[i][r];
        int key = i * 16 + (lh << 2) + r;
        if (hg) pv *= sG[key];
        int slot = (key >> 3) ^ (l16 & 7);
        *(unsigned short*)(sPw + l16 * 128 + (slot << 4) + (key & 7) * 2) = f2bf(pv);
      }

    // ---- PV: A = P [16q][64key], B = V [key][d] from sV[d][key] ----
#pragma unroll
    for (int s = 0; s < 2; ++s) {
      bf16x8 pf = *(const bf16x8*)(sPw + l16 * 128 + ((((s << 2) + lh) ^ (l16 & 7)) << 4));
#pragma unroll
      for (int jb = 0; jb < 4; ++jb) {
        int vr = jb * 16 + l16;
        bf16x8 vf = *(const bf16x8*)(sV + vr * 128 + ((((s << 2) + lh) ^ (vr & 7)) << 4));
        accO[jb] = __builtin_amdgcn_mfma_f32_16x16x32_bf16(pf, vf, accO[jb], 0, 0, 0);
      }
    }
  }
#undef LOADT

  // ---- epilogue ----
  float linv = 1.f / l_;
#pragma unroll
  for (int r = 0; r < 4; ++r) {
    float li = __shfl(linv, (lh << 2) + r);
    int q = q0 + w * 16 + (lh << 2) + r;
    if (q >= DWT_) continue;
#pragma unroll
    for (int jb = 0; jb < 4; ++jb) {
      Oz[(size_t)(bD + q) * 512 + h64 + jb * 16 + l16] = f2bf(accO[jb][r] * li);
    }
  }
}

// ---------------------------------------------------------------------------
// fused LayerNorm, all residual inputs bf16 -> bf16 outputs (fp32 internal)
__global__ __launch_bounds__(256) void k_ln2(
    const unsigned short* __restrict__ llseq, const unsigned short* __restrict__ llout,
    const unsigned short* __restrict__ crossp,
    const unsigned short* __restrict__ lhseq, const unsigned short* __restrict__ lhout,
    const float* __restrict__ g, const float* __restrict__ beta,
    unsigned short* __restrict__ llf, unsigned short* __restrict__ lhf)
{
  __shared__ float red[256], red2[256];
  int row = blockIdx.x, tid = threadIdx.x, zz = blockIdx.y;
  const unsigned short* a  = zz ? lhseq : llseq;
  const unsigned short* b2 = zz ? lhout : llout;
  const unsigned short* c  = zz ? nullptr : crossp;
  const float* gg = g + zz * D_;
  const float* bb = beta + zz * D_;
  unsigned short* outp = zz ? lhf : llf;
  size_t base = (size_t)row * D_ + 2 * tid;
  unsigned av = *(const unsigned*)(a + base);
  unsigned bv = *(const unsigned*)(b2 + base);
  float v0 = bf2f((unsigned short)av) + bf2f((unsigned short)bv);
  float v1 = bf2f((unsigned short)(av >> 16)) + bf2f((unsigned short)(bv >> 16));
  if (c) {
    unsigned cv = *(const unsigned*)(c + base);
    v0 += bf2f((unsigned short)cv);
    v1 += bf2f((unsigned short)(cv >> 16));
  }
  red[tid] = v0 + v1; red2[tid] = v0 * v0 + v1 * v1;
  __syncthreads();
  for (int o = 128; o > 0; o >>= 1) {
    if (tid < o) { red[tid] += red[tid + o]; red2[tid] += red2[tid + o]; }
    __syncthreads();
  }
  float mu = red[0] / (float)D_;
  float var = red2[0] / (float)D_ - mu * mu;
  float rstd = rsqrtf(var + 1e-5f);
  float y0 = (v0 - mu) * rstd * gg[2 * tid] + bb[2 * tid];
  float y1 = (v1 - mu) * rstd * gg[2 * tid + 1] + bb[2 * tid + 1];
  *(unsigned*)(outp + base) = (unsigned)f2bf(y0) | ((unsigned)f2bf(y1) << 16);
}

// ---------------------------------------------------------------------------
// merged: blocks 0..1021 head_partial (head_W chunk staged through LDS, each
// byte fetched once; 192 compute threads own full (b, 4-pred) outputs);
// 1022..1533 recon with coalesced 16-o-chunk writes.
__global__ __launch_bounds__(512) void k_headrec(
    const float* __restrict__ llo, const float* __restrict__ lho,
    const float* __restrict__ llg, const float* __restrict__ lhg,
    const float* __restrict__ hw, float* __restrict__ part,
    const float* __restrict__ h, const float* __restrict__ g,
    float* __restrict__ outp)
{
  __shared__ float lds[8][520];   // +8 pad: 8 pb-broadcast rows spread banks
  __shared__ float sW[6144];      // 64 k-rows x 96 preds (24KB chunk)
  int bid = blockIdx.x, tid = threadIdx.x;
  if (bid < 2 * DWT_) {
    int x = bid;
    int branch = x / DWT_, t = x % DWT_;
    const float* seq = branch ? lho : llo;
    const float* gt  = branch ? lhg : llg;
    for (int i = tid; i < 4096; i += 512) {
      int b = i >> 9, d = i & 511;
      lds[b][d] = seq[((size_t)b * DWT_ + t) * D_ + d] * gt[(size_t)t * D_ + d];
    }
    const bool act = tid < 192;
    const int pb_ = tid / 24, j = tid % 24;   // b 0..7, pred-quad 0..23
    f32x4 acc = (f32x4){0.f, 0.f, 0.f, 0.f};
    const float* hwx = hw + (size_t)x * (D_ * 96);
    for (int c = 0; c < 8; ++c) {
      __syncthreads();
      // cooperative stage of 64 k-rows (6144 floats), perfectly coalesced
      {
        const float* src = hwx + (size_t)c * 6144 + tid * 12;
        float4 v0 = *(const float4*)(src);
        float4 v1 = *(const float4*)(src + 4);
        float4 v2 = *(const float4*)(src + 8);
        *(float4*)&sW[tid * 12]     = v0;
        *(float4*)&sW[tid * 12 + 4] = v1;
        *(float4*)&sW[tid * 12 + 8] = v2;
      }
      __syncthreads();
      if (act) {
        int k0 = c * 64;
#pragma unroll 8
        for (int k = 0; k < 64; ++k) {
          float s = lds[pb_][k0 + k];
          float4 wv = *(const float4*)&sW[k * 96 + j * 4];
          acc[0] += s * wv.x; acc[1] += s * wv.y;
          acc[2] += s * wv.z; acc[3] += s * wv.w;
        }
      }
    }
    if (act)
      *(f32x4*)&part[(size_t)x * 768 + pb_ * 96 + j * 4] = acc;
  } else {
    int rid = bid - 2 * DWT_;
    int b = rid >> 6, ot = rid & 63;
    int o0 = ot << 4;
    int d = tid;
    float h4[4], g4[4];
#pragma unroll
    for (int k = 0; k < 4; ++k) { h4[k] = h[d * 4 + k]; g4[k] = g[d * 4 + k]; }
    int tb = (o0 >> 1) - 1;
    float rl[10], rh[10];
#pragma unroll
    for (int k = 0; k < 10; ++k) {
      int t = tb + k;
      bool ok = (t >= 0 && t < DWT_);
      size_t ix = ((size_t)(b * DWT_ + (ok ? t : 0))) * D_ + d;
      rl[k] = ok ? llo[ix] : 0.f;
      rh[k] = ok ? lho[ix] : 0.f;
    }
    float* ob = outp + ((size_t)(b * D_ + d)) * RECON_LEN + o0;
#pragma unroll
    for (int j2 = 0; j2 < 16; ++j2) {
      int o = o0 + j2;
      float acc;
      if ((j2 & 1) == 0) {
        int ix = (j2 >> 1) + 1;
        acc = rl[ix - 1] * h4[3] + rh[ix - 1] * g4[3] + rl[ix] * h4[1] + rh[ix] * g4[1];
      } else {
        int ix = ((j2 - 1) >> 1) + 1;
        acc = rl[ix] * h4[2] + rh[ix] * g4[2] + rl[ix + 1] * h4[0] + rh[ix + 1] * g4[0];
      }
      if (o < RECON_LEN) ob[j2] = acc;
    }
  }
}

// wave-per-(b,p) reduction over 1022 chunks (round-12 version: 768 waves
// of parallelism beats coalescing for this small latency-bound reduction)
__global__ __launch_bounds__(256) void k_head_final(const float* __restrict__ part,
    const float* __restrict__ hb, const float* __restrict__ rw,
    const float* __restrict__ rb, const float* __restrict__ meanp,
    const float* __restrict__ stdp, float* __restrict__ preds)
{
  int wv = (blockIdx.x << 2) + (threadIdx.x >> 6);
  int lane = threadIdx.x & 63;
  if (wv >= 768) return;
  int b = wv / 96, p = wv - b * 96;
  float s = 0.f;
  for (int c = lane; c < 2 * DWT_; c += 64) s += part[(size_t)c * 768 + b * 96 + p];
#pragma unroll
  for (int off = 32; off; off >>= 1) s += __shfl_xor(s, off);
  if (lane == 0) {
    float acc = s + hb[p];
    preds[b * 96 + p] = (acc - rb[0]) / (rw[0] + 1e-10f) * stdp[b] + meanp[b];
  }
}

// ---------------------------------------------------------------------------
extern "C" void kernel_launch(void* const* d_in, const int* in_sizes, int n_in,
                              void* d_out, int out_size, void* d_ws, size_t ws_size,
                              hipStream_t stream)
{
  const float* x       = (const float*)d_in[0];
  const float* revin_w = (const float*)d_in[1];
  const float* revin_b = (const float*)d_in[2];
  const float* patch_W = (const float*)d_in[3];
  const float* patch_b = (const float*)d_in[4];
  const float* pos_emb = (const float*)d_in[5];
  const float* dwt_h   = (const float*)d_in[6];
  const float* dwt_g   = (const float*)d_in[7];
  const float* raw_tau = (const float*)d_in[8];
  const float* attn_W  = (const float*)d_in[9];
  const float* attn_b  = (const float*)d_in[10];
  const float* mlp_W1  = (const float*)d_in[11];
  const float* mlp_b1  = (const float*)d_in[12];
  const float* mlp_W2  = (const float*)d_in[13];
  const float* mlp_b2  = (const float*)d_in[14];
  const float* ln_g    = (const float*)d_in[15];
  const float* ln_b    = (const float*)d_in[16];
  const float* ll_gate = (const float*)d_in[17];
  const float* lh_gate = (const float*)d_in[18];
  const float* head_W  = (const float*)d_in[19];
  const float* head_b  = (const float*)d_in[20];

  float* ws  = (float*)d_ws;
  float* out = (float*)d_out;

  float* meanp = ws + WS_MEAN;
  float* stdp  = ws + WS_STD;
  float* xn    = ws + WS_XN;
  float* pseq  = ws + WS_PSEQ;
  float* gateb = ws + WS_GATE;
  float* llo   = ws + WS_LLO;
  float* lho   = ws + WS_LHO;
  float* part  = ws + WS_PART;

  unsigned short* llseq16 = (unsigned short*)(ws + WS_LLSEQ);
  unsigned short* lhseq16 = (unsigned short*)(ws + WS_LHSEQ);
  unsigned short* cross16 = (unsigned short*)(ws + WS_CROSS);
  unsigned short* llf16 = (unsigned short*)(ws + WS_LLF);
  unsigned short* lhf16 = (unsigned short*)(ws + WS_LHF);
  unsigned short* Qb16  = (unsigned short*)(ws + WS_QB);
  unsigned short* Kb16  = (unsigned short*)(ws + WS_KB);
  unsigned short* Vt16  = (unsigned short*)(ws + WS_VT);
  unsigned short* Ob16  = (unsigned short*)(ws + WS_OB);
  unsigned short* hid16 = (unsigned short*)(ws + WS_HID2);
  unsigned short* llout16 = (unsigned short*)(ws + WS_LLO16);
  unsigned short* lhout16 = llout16 + 2093056;

  unsigned short* wt  = (unsigned short*)(ws + WS_WT);    // bf16 weights (own region)
  unsigned short* w1t = wt + 12 * 262144;                 // 2 x [2048][512]
  unsigned short* w2t = w1t + 2 * 1048576;                // 2 x [512][2048]

  // ---- stage 0: RevIN + (patch|weight-prep) + (transpose|DWT+gate) ----
  k_revin<<<8, 256, 0, stream>>>(x, revin_w, revin_b, meanp, stdp, xn);
  k_pw<<<8184 + 7168, 512, 0, stream>>>(xn, patch_W, patch_b, pos_emb, pseq,
                                        attn_W, mlp_W1, mlp_W2, wt, w1t, w2t);
  k_td<<<4096 + 256, 512, 0, stream>>>(pseq, out + PATCHES_O, dwt_h, dwt_g,
                                       llseq16, lhseq16, out + OUT_LL_O,
                                       out + OUT_LH_O, raw_tau, gateb);

  // ---- stage 1: LL + LH MHAs batched ----
  k_gemm_mfma<64,3><<<dim3(12, 64, 2), 256, 0, stream>>>(
      llseq16, llseq16, lhseq16, lhseq16, wt, attn_b, nullptr, nullptr,
      Qb16, Kb16, Vt16, MR_, 1536, D_, 0, 4 * 262144, 2048);
  k_mattn<<<dim3(64, 8, 2), 256, 0, stream>>>(Qb16, Kb16, Vt16, gateb, Ob16);
  k_gemm_mfma<64,1><<<dim3(4, 64, 2), 256, 0, stream>>>(
      Ob16, nullptr, Ob16 + (size_t)2093056, nullptr, wt + 3 * 262144,
      attn_b + 1536, nullptr, nullptr, llout16, lhout16, nullptr,
      MR_, D_, D_, 0, 4 * 262144, 2048);

  // ---- cross MHA: Q from llout16, K/V from lhout16 ----
  k_gemm_mfma<64,3><<<dim3(12, 64, 1), 256, 0, stream>>>(
      llout16, lhout16, nullptr, nullptr, wt + 8 * 262144, attn_b + 2 * 2048,
      nullptr, nullptr, Qb16, Kb16, Vt16, MR_, 1536, D_, 0, 0, 0);
  k_mattn<<<dim3(64, 8, 1), 256, 0, stream>>>(Qb16, Kb16, Vt16, nullptr, Ob16);
  k_gemm_mfma<64,1><<<dim3(4, 64, 1), 256, 0, stream>>>(
      Ob16, nullptr, nullptr, nullptr, wt + 11 * 262144, attn_b + 2 * 2048 + 1536,
      nullptr, nullptr, cross16, nullptr, nullptr, MR_, D_, D_, 0, 0, 0);

  // ---- stage 2: fused LN (bf16) + batched MLP ----
  k_ln2<<<dim3(MR_, 2), 256, 0, stream>>>(llseq16, llout16, cross16,
                                          lhseq16, lhout16, ln_g, ln_b,
                                          llf16, lhf16);
  k_gemm_mfma<128,1><<<dim3(16, 32, 2), 256, 0, stream>>>(
      llf16, nullptr, lhf16, nullptr, w1t, mlp_b1, nullptr, nullptr,
      hid16, hid16 + (size_t)4088 * 2048, nullptr, MR_, DFF_, D_, 1,
      1048576, 2048);
  k_gemm_mfma<64,0,1><<<dim3(4, 64, 2), 256, 0, stream>>>(
      hid16, nullptr, hid16 + (size_t)4088 * 2048, nullptr, w2t, mlp_b2,
      llf16, lhf16, llo, lho, nullptr, MR_, D_, DFF_, 0, 1048576, 512);

  // ---- stage 3: (head_partial | recon) merged + head_final ----
  k_headrec<<<2 * DWT_ + 512, 512, 0, stream>>>(llo, lho, ll_gate, lh_gate,
                                                head_W, part, dwt_h, dwt_g,
                                                out + RECON_O);
  k_head_final<<<192, 256, 0, stream>>>(part, head_b, revin_w, revin_b, meanp, stdp,
                                        out + PREDS_O);
}

// Round 16
// 384.131 us; speedup vs baseline: 1.1929x; 1.0369x over previous
//
#include <hip/hip_runtime.h>
#include <math.h>

#define B_    8
#define SEQ_  8192
#define D_    512
#define N_    1023
#define DWT_  511
#define DFF_  2048
#define MR_   (B_ * DWT_)          // 4088 rows for all [B*L, D] GEMMs

// ---------------- d_out layout (flat concat of the 5 outputs) ----------------
#define PREDS_O    0
#define RECON_O    768
#define RECON_LEN  1022
#define PATCHES_O  (RECON_O + 8*512*1022)   // 4186880
#define OUT_LL_O   (PATCHES_O + 8*512*1023) // 8377088
#define OUT_LH_O   (OUT_LL_O + 8*512*511)   // 10470144

// ---------------- workspace layout (float units) ----------------
#define WS_MEAN   ((size_t)0)
#define WS_STD    ((size_t)8)
#define WS_XN     ((size_t)16)
#define WS_PSEQ   ((size_t)65552)
#define WS_LLSEQ  ((size_t)4255760)    // bf16 [4088][512]
#define WS_LHSEQ  ((size_t)6348816)    // bf16
#define WS_CROSS  ((size_t)21000208)   // bf16 [4088][512] (cross16)
#define WS_GATE   ((size_t)23093264)
#define WS_LLF    ((size_t)23097352)   // bf16 [4088][512]
#define WS_LHF    ((size_t)25190408)   // bf16
#define WS_LLO    ((size_t)16814096)   // fp32 [4088][512] (MLP out, LL)
#define WS_LHO    ((size_t)18907152)   // fp32 (LH)
#define WS_PART   WS_CROSS             // head partials alias cross (disjoint phase)
// bf16 buffers beyond the old arena (ws ~766MiB)
#define WS_QB     ((size_t)27283464)   // 2 x [4088][512] bf16
#define WS_KB     (WS_QB + 2093056)
#define WS_VT     (WS_KB + 2093056)    // 2 x [4096][512] bf16
#define WS_OB     (WS_VT + 2097152)
#define WS_HID2   (WS_OB + 2093056)    // 2 x [4088][2048] bf16
#define WS_LLO16  (WS_HID2 + 8372224)  // 2 x [4088][512] bf16 (llout16, lhout16)
#define WS_WT     ((size_t)48218120)   // bf16 weight arena (own region, no alias!)

using bf16x8 = __attribute__((ext_vector_type(8))) short;
using u16x8  = __attribute__((ext_vector_type(8))) unsigned short;
using f32x4  = __attribute__((ext_vector_type(4))) float;

__device__ inline unsigned short f2bf(float f) {
  unsigned u = __float_as_uint(f);
  u += 0x7fffu + ((u >> 16) & 1u);    // round-to-nearest-even
  return (unsigned short)(u >> 16);
}
__device__ inline float bf2f(unsigned short h) {
  return __uint_as_float(((unsigned)h) << 16);
}

// async global->LDS DMA, 16B per lane; lds base must be wave-uniform.
__device__ __forceinline__ void gld16(const void* g, void* lds) {
  __builtin_amdgcn_global_load_lds(
      (const __attribute__((address_space(1))) unsigned int*)g,
      (__attribute__((address_space(3))) unsigned int*)lds, 16, 0, 0);
}

// ---------------------------------------------------------------------------
__global__ __launch_bounds__(256) void k_revin(const float* __restrict__ x,
    const float* __restrict__ rw, const float* __restrict__ rb,
    float* __restrict__ meanp, float* __restrict__ stdp, float* __restrict__ xn)
{
  __shared__ float rs[256], rs2[256];
  int b = blockIdx.x, tid = threadIdx.x;
  const float* xb = x + (size_t)b * SEQ_;
  float s = 0.f, s2 = 0.f;
  for (int i = tid; i < SEQ_; i += 256) { float v = xb[i]; s += v; s2 += v * v; }
  rs[tid] = s; rs2[tid] = s2; __syncthreads();
  for (int o = 128; o > 0; o >>= 1) {
    if (tid < o) { rs[tid] += rs[tid + o]; rs2[tid] += rs2[tid + o]; }
    __syncthreads();
  }
  float mu = rs[0] / SEQ_;
  float var = rs2[0] / SEQ_ - mu * mu;
  float sd = sqrtf(var + 1e-5f);
  if (tid == 0) { meanp[b] = mu; stdp[b] = sd; }
  float w = rw[0], bb = rb[0], inv = 1.f / sd;
  for (int i = tid; i < SEQ_; i += 256)
    xn[(size_t)b * SEQ_ + i] = (xb[i] - mu) * inv * w + bb;
}

// ---------------------------------------------------------------------------
// merged: blocks 0..8183 patch-embed; 8184..15351 weight transpose+convert.
__global__ __launch_bounds__(512) void k_pw(const float* __restrict__ xn,
    const float* __restrict__ pW, const float* __restrict__ pb,
    const float* __restrict__ pos, float* __restrict__ p_seq,
    const float* __restrict__ attn_W, const float* __restrict__ mlp_W1,
    const float* __restrict__ mlp_W2, unsigned short* __restrict__ wt,
    unsigned short* __restrict__ w1t, unsigned short* __restrict__ w2t)
{
  __shared__ float sx[16];
  __shared__ float tl[32][33];
  int bid = blockIdx.x, tid = threadIdx.x;
  if (bid < 8184) {
    int n = bid % N_, b = bid / N_, d = tid;
    if (tid < 16) sx[tid] = xn[(size_t)b * SEQ_ + n * 8 + tid];
    __syncthreads();
    float acc = pb[d] + pos[(size_t)n * D_ + d];
#pragma unroll
    for (int k = 0; k < 16; ++k) acc += sx[k] * pW[k * D_ + d];
    p_seq[((size_t)b * N_ + n) * D_ + d] = acc;
  } else {
    int b2 = bid - 8184;
    const float* src; unsigned short* dst; int K, N, nx, ky;
    if (b2 < 3072) {
      int z = b2 >> 8, r = b2 & 255;
      nx = r & 15; ky = r >> 4; K = 512; N = 512;
      src = attn_W + (size_t)z * 262144; dst = wt + (size_t)z * 262144;
    } else if (b2 < 5120) {
      int b3 = b2 - 3072; int z = b3 >> 10, r = b3 & 1023;
      nx = r & 63; ky = r >> 6; K = 512; N = 2048;
      src = mlp_W1 + (size_t)z * 1048576; dst = w1t + (size_t)z * 1048576;
    } else {
      int b4 = b2 - 5120; int z = b4 >> 10, r = b4 & 1023;
      nx = r & 15; ky = r >> 4; K = 2048; N = 512;
      src = mlp_W2 + (size_t)z * 1048576; dst = w2t + (size_t)z * 1048576;
    }
    int n0 = nx * 32, k0 = ky * 32;
    int tx = tid & 31, ty = tid >> 5;    // ty 0..15
#pragma unroll
    for (int r = 0; r < 2; ++r)
      tl[ty + 16 * r][tx] = src[(size_t)(k0 + ty + 16 * r) * N + n0 + tx];
    __syncthreads();
#pragma unroll
    for (int r = 0; r < 2; ++r)
      dst[(size_t)(n0 + ty + 16 * r) * K + k0 + tx] = f2bf(tl[tx][ty + 16 * r]);
  }
}

// ---------------------------------------------------------------------------
// merged: blocks 0..4095 transpose pseq -> patches; 4096..4351 DWT+gate with
// coalesced [d][t]-chunk writes (16 consecutive t per thread = 64B/lane).
__global__ __launch_bounds__(512) void k_td(const float* __restrict__ p_seq,
    float* __restrict__ patches, const float* __restrict__ h,
    const float* __restrict__ g, unsigned short* __restrict__ ll_seq,
    unsigned short* __restrict__ lh_seq, float* __restrict__ ll_out,
    float* __restrict__ lh_out, const float* __restrict__ raw_tau,
    float* __restrict__ gate)
{
  __shared__ float tile[32][33];
  __shared__ float gpart[16][8];
  int bid = blockIdx.x, tid = threadIdx.x;
  if (bid < 4096) {
    int d0 = (bid & 15) * 32, n0 = ((bid >> 4) & 31) * 32, b = bid >> 9;
    int tx = tid & 31, ty = tid >> 5;   // ty 0..15
#pragma unroll
    for (int r = 0; r < 2; ++r) {
      int n = n0 + ty + 16 * r;
      if (n < N_) tile[ty + 16 * r][tx] = p_seq[((size_t)b * N_ + n) * D_ + d0 + tx];
    }
    __syncthreads();
#pragma unroll
    for (int r = 0; r < 2; ++r) {
      int d = d0 + ty + 16 * r, n = n0 + tx;
      if (n < N_) patches[((size_t)b * D_ + d) * N_ + n] = tile[tx][ty + 16 * r];
    }
  } else {
    int idx = bid - 4096;               // 0..255
    int b = idx >> 5, tt = idx & 31;
    int t0 = tt << 4;
    int d = tid;
    float h4[4], g4[4];
#pragma unroll
    for (int k = 0; k < 4; ++k) { h4[k] = h[d * 4 + k]; g4[k] = g[d * 4 + k]; }
    float llv[16], lhv[16], av[16];
#pragma unroll
    for (int i = 0; i < 16; ++i) {
      int t = t0 + i;
      float ah = 0.f, ag = 0.f;
      if (t < DWT_) {
#pragma unroll
        for (int k = 0; k < 4; ++k) {
          int n = 2 * t + k - 1;
          if (n >= 0 && n < N_) {
            float v = p_seq[((size_t)b * N_ + n) * D_ + d];
            ah += v * h4[k]; ag += v * g4[k];
          }
        }
      }
      llv[i] = ah; lhv[i] = ag; av[i] = fabsf(ag);
    }
    // bf16 sequence writes ([t][d]-major, coalesced)
#pragma unroll
    for (int i = 0; i < 16; ++i) {
      int t = t0 + i;
      if (t < DWT_) {
        ll_seq[((size_t)b * DWT_ + t) * D_ + d] = f2bf(llv[i]);
        lh_seq[((size_t)b * DWT_ + t) * D_ + d] = f2bf(lhv[i]);
      }
    }
    // fp32 d_out writes: 16 consecutive t per thread = one 64B line per lane
    size_t ob = ((size_t)b * D_ + d) * DWT_ + t0;
#pragma unroll
    for (int i = 0; i < 16; ++i) {
      if (t0 + i < DWT_) { ll_out[ob + i] = llv[i]; lh_out[ob + i] = lhv[i]; }
    }
    // gate: butterfly-reduce each of 16 t's across the wave, then LDS combine
#pragma unroll
    for (int off = 1; off < 64; off <<= 1)
#pragma unroll
      for (int i = 0; i < 16; ++i) av[i] += __shfl_xor(av[i], off);
    int lane = tid & 63, w = tid >> 6;
    if (lane == 0) {
#pragma unroll
      for (int i = 0; i < 16; ++i) gpart[i][w] = av[i];
    }
    __syncthreads();
    if (tid < 16) {
      float s = 0.f;
#pragma unroll
      for (int w2 = 0; w2 < 8; ++w2) s += gpart[tid][w2];
      int t = t0 + tid;
      if (t < DWT_) {
        float tau = 1.f / (1.f + expf(-raw_tau[0]));
        float e = s / (float)D_;
        gate[(size_t)b * DWT_ + t] = 1.f / (1.f + expf(-(e - tau) * 10.f));
      }
    }
  }
}

// ---------------------------------------------------------------------------
// C = A(bf16) @ WT(bf16 [N][K])^T + bias (+res) (opt gelu) via MFMA, z-batched.
// 2-phase double-buffered K-loop with counted vmcnt (DMA stays in flight).
// XCD-chunked bijective block swizzle (all grids have nwg%8==0): blocks on
// one XCD share A-panels -> A stays L2-resident (kills 8x fetch amplification).
// CMODE 0: fp32 C[m][n] (+res; RESBF: residual bf16). 1: bf16 C[m][n].
// CMODE 3: fused QKV: n<512->Q bf16; <1024->K bf16; >=1024->V transposed.
template<int BM, int CMODE, int RESBF = 0>
__global__ __launch_bounds__(256, BM == 64 ? 3 : 2) void k_gemm_mfma(
    const void* __restrict__ A00, const void* __restrict__ A01,
    const void* __restrict__ A10, const void* __restrict__ A11,
    const unsigned short* __restrict__ WT, const float* __restrict__ bias,
    const void* __restrict__ res0, const void* __restrict__ res1,
    void* __restrict__ C0, void* __restrict__ C1, void* __restrict__ C2,
    int M, int N, int K, int act, int zsW, int zsB)
{
  __shared__ unsigned char lds[2][(BM + 128) * 128];

  const int tid = threadIdx.x;
  const int wid = tid >> 6, lane = tid & 63;

  // ---- XCD-chunked bijective swizzle of the flattened grid ----
  const int gx = gridDim.x, gxy = gridDim.x * gridDim.y;
  const int nwg = gxy * gridDim.z;
  int lin = blockIdx.z * gxy + blockIdx.y * gx + blockIdx.x;
  int swz = (lin & 7) * (nwg >> 3) + (lin >> 3);     // nwg % 8 == 0 for all grids
  const int z = swz / gxy;
  int rem = swz - z * gxy;
  const int n0 = (rem % gx) * 128, m0 = (rem / gx) * BM;

  constexpr int MI = 4;
  constexpr int NI = (BM == 128) ? 4 : 2;
  const int wrow = (BM == 128) ? (wid >> 1) * 64 : 0;
  const int wcol = (BM == 128) ? (wid & 1) * 64 : wid * 32;
  const int l16 = lane & 15, lh = lane >> 4;

  const unsigned short* wt_ = WT + (size_t)z * zsW;
  const float* bias_ = bias + (size_t)z * zsB;
  const unsigned short* Ap;
  if (CMODE == 3) Ap = (const unsigned short*)(z ? (n0 < 512 ? A10 : A11)
                                                 : (n0 < 512 ? A00 : A01));
  else            Ap = (const unsigned short*)(z ? A10 : A00);

  f32x4 acc[MI][NI];
#pragma unroll
  for (int i = 0; i < MI; ++i)
#pragma unroll
    for (int j = 0; j < NI; ++j) acc[i][j] = (f32x4){0.f, 0.f, 0.f, 0.f};

  const int nk = K >> 6;
  auto stage = [&](int t, int buf) {
    unsigned char* sA = lds[buf];
    unsigned char* sB = lds[buf] + BM * 128;
    int k0 = t << 6;
    constexpr int PA = BM / 32;
#pragma unroll
    for (int p = 0; p < PA; ++p) {
      int s0 = wid * (BM * 2) + p * 64;
      int s = s0 + lane;
      int row = s >> 3, oct = s & 7;
      int gr = m0 + row; if (gr > M - 1) gr = M - 1;
      gld16(Ap + (size_t)gr * K + k0 + ((oct ^ (row & 7)) << 3),
            sA + (size_t)s0 * 16);
    }
#pragma unroll
    for (int p = 0; p < 4; ++p) {
      int s0 = wid * 256 + p * 64;
      int s = s0 + lane;
      int row = s >> 3, oct = s & 7;
      gld16(wt_ + (size_t)(n0 + row) * K + k0 + ((oct ^ (row & 7)) << 3),
            sB + (size_t)s0 * 16);
    }
  };

  stage(0, 0);
  for (int t = 0; t < nk; ++t) {
    const int cur = t & 1;
    if (t + 1 < nk) {
      stage(t + 1, cur ^ 1);
      if constexpr (BM == 64) asm volatile("s_waitcnt vmcnt(6)" ::: "memory");
      else                    asm volatile("s_waitcnt vmcnt(8)" ::: "memory");
    } else {
      asm volatile("s_waitcnt vmcnt(0)" ::: "memory");
    }
    __builtin_amdgcn_sched_barrier(0);
    __builtin_amdgcn_s_barrier();
    __builtin_amdgcn_sched_barrier(0);
    unsigned char* sA = lds[cur];
    unsigned char* sB = lds[cur] + BM * 128;
#pragma unroll
    for (int s = 0; s < 2; ++s) {
      bf16x8 af[MI], bfr[NI];
#pragma unroll
      for (int i = 0; i < MI; ++i) {
        int r = wrow + i * 16 + l16;
        af[i] = *(const bf16x8*)(sA + r * 128 + (((s * 4 + lh) ^ (r & 7)) << 4));
      }
#pragma unroll
      for (int j = 0; j < NI; ++j) {
        int r = wcol + j * 16 + l16;
        bfr[j] = *(const bf16x8*)(sB + r * 128 + (((s * 4 + lh) ^ (r & 7)) << 4));
      }
#pragma unroll
      for (int i = 0; i < MI; ++i)
#pragma unroll
        for (int j = 0; j < NI; ++j)
          acc[i][j] = __builtin_amdgcn_mfma_f32_16x16x32_bf16(af[i], bfr[j],
                                                              acc[i][j], 0, 0, 0);
    }
    __builtin_amdgcn_sched_barrier(0);
    __builtin_amdgcn_s_barrier();
  }
  // ---- epilogue ----
  const void* res_ = z ? res1 : res0;
#pragma unroll
  for (int i = 0; i < MI; ++i) {
#pragma unroll
    for (int r = 0; r < 4; ++r) {
      int m = m0 + wrow + i * 16 + lh * 4 + r;
      if (m >= M) continue;
#pragma unroll
      for (int j = 0; j < NI; ++j) {
        int n = n0 + wcol + j * 16 + l16;
        float v = acc[i][j][r] + bias_[n];
        if (act) v = 0.5f * v * (1.f + erff(v * 0.70710678118654752f));
        if (CMODE == 0) {
          float* Cp = (float*)(z ? C1 : C0);
          if (res_) {
            float rv = RESBF ? bf2f(((const unsigned short*)res_)[(size_t)m * N + n])
                             : ((const float*)res_)[(size_t)m * N + n];
            v += rv;
          }
          Cp[(size_t)m * N + n] = v;
        } else if (CMODE == 1) {
          unsigned short* Cp = (unsigned short*)(z ? C1 : C0);
          Cp[(size_t)m * N + n] = f2bf(v);
        } else {
          if (n < 512) {
            ((unsigned short*)C0)[(size_t)z * 2093056 + (size_t)m * 512 + n] = f2bf(v);
          } else if (n < 1024) {
            ((unsigned short*)C1)[(size_t)z * 2093056 + (size_t)m * 512 + (n - 512)] = f2bf(v);
          } else {
            int bb = m / DWT_;
            int key = m - bb * DWT_;
            ((unsigned short*)C2)[(size_t)z * 2097152 +
                ((size_t)(bb * 512 + (n - 1024))) * 512 + key] = f2bf(v);
          }
        }
      }
    }
  }
}

// ---------------------------------------------------------------------------
// MFMA flash attention, z-batched, register-prefetched K/V staging (T14).
__global__ __launch_bounds__(256) void k_mattn(
    const unsigned short* __restrict__ Qb, const unsigned short* __restrict__ Kb,
    const unsigned short* __restrict__ Vt, const float* __restrict__ gate,
    unsigned short* __restrict__ Ob)
{
  __shared__ unsigned char sQ[8192], sK[8192], sV[8192], sP[8192];
  __shared__ float sG[64];

  const int bh = blockIdx.x;
  const int b = bh >> 3;
  const int q0 = blockIdx.y * 64;
  const int z = blockIdx.z;
  const int tid = threadIdx.x;
  const int w = tid >> 6, lane = tid & 63;
  const int l16 = lane & 15, lh = lane >> 4;
  const bool hg = (z == 1) && (gate != nullptr);
  const int bD = b * DWT_;

  const unsigned short* Qz = Qb + (size_t)z * 2093056;
  const unsigned short* Kz = Kb + (size_t)z * 2093056;
  const unsigned short* Vz = Vt + (size_t)z * 2097152;
  unsigned short* Oz = Ob + (size_t)z * 2093056;
  const int h64 = (bh & 7) * 64;
  const unsigned short* vrow = Vz + (size_t)bh * 64 * 512;

  // stage Q tile [64 q][64 d]
#pragma unroll
  for (int it = 0; it < 2; ++it) {
    int i = it * 256 + tid;
    int row = i >> 3, oct = i & 7;
    int qr = q0 + row; if (qr > DWT_ - 1) qr = DWT_ - 1;
    u16x8 v = *(const u16x8*)(Qz + (size_t)(bD + qr) * 512 + h64 + oct * 8);
    *(u16x8*)(sQ + row * 128 + ((oct ^ (row & 7)) << 4)) = v;
  }

  // preload full gate vector (2 keys per thread)
  float ga = 0.f, gb2 = 0.f;
  if (hg) {
    int k = 2 * tid;
    ga  = (k     < DWT_) ? gate[(size_t)bD + k]     : 0.f;
    gb2 = (k + 1 < DWT_) ? gate[(size_t)bD + k + 1] : 0.f;
  }

  float m_ = -1e30f, l_ = 0.f;
  f32x4 accO[4];
#pragma unroll
  for (int jb = 0; jb < 4; ++jb) accO[jb] = (f32x4){0.f, 0.f, 0.f, 0.f};

  unsigned char* sPw = sP + w * 2048;   // wave-private [16 q][64 key] bf16

  uint4 pk0, pk1, pv0, pv1;
#define LOADT(kt_) do {                                                      \
    int k0_ = (kt_) * 64;                                                    \
    int row_ = tid >> 3, oct_ = tid & 7;                                     \
    int kr0_ = k0_ + row_;      if (kr0_ > DWT_ - 1) kr0_ = DWT_ - 1;        \
    int kr1_ = k0_ + row_ + 32; if (kr1_ > DWT_ - 1) kr1_ = DWT_ - 1;        \
    pk0 = *(const uint4*)(Kz + (size_t)(bD + kr0_) * 512 + h64 + oct_ * 8);  \
    pk1 = *(const uint4*)(Kz + (size_t)(bD + kr1_) * 512 + h64 + oct_ * 8);  \
    pv0 = *(const uint4*)(vrow + (size_t)row_ * 512 + k0_ + oct_ * 8);       \
    pv1 = *(const uint4*)(vrow + (size_t)(row_ + 32) * 512 + k0_ + oct_ * 8);\
  } while (0)

  LOADT(0);
  for (int kt = 0; kt < 8; ++kt) {
    const int k0 = kt * 64;
    __syncthreads();                    // prior-iter PV reads complete
    {
      int row = tid >> 3, oct = tid & 7, row1 = (tid >> 3) + 32;
      *(uint4*)(sK + row  * 128 + ((oct ^ (row  & 7)) << 4)) = pk0;
      *(uint4*)(sK + row1 * 128 + ((oct ^ (row1 & 7)) << 4)) = pk1;
      *(uint4*)(sV + row  * 128 + ((oct ^ (row  & 7)) << 4)) = pv0;
      *(uint4*)(sV + row1 * 128 + ((oct ^ (row1 & 7)) << 4)) = pv1;
    }
    if (hg && (tid >> 5) == kt) {
      sG[(tid & 31) * 2]     = ga;
      sG[(tid & 31) * 2 + 1] = gb2;
    }
    __syncthreads();
    if (kt < 7) LOADT(kt + 1);          // prefetch next tile under compute

    // ---- S^T strip: rows = 64 keys (4 blocks), cols = wave's 16 q ----
    f32x4 sacc[4];
#pragma unroll
    for (int i = 0; i < 4; ++i) sacc[i] = (f32x4){0.f, 0.f, 0.f, 0.f};
#pragma unroll
    for (int s = 0; s < 2; ++s) {
      int qr = w * 16 + l16;
      bf16x8 qf = *(const bf16x8*)(sQ + qr * 128 + ((((s << 2) + lh) ^ (qr & 7)) << 4));
#pragma unroll
      for (int i = 0; i < 4; ++i) {
        int krr = i * 16 + l16;
        bf16x8 kf = *(const bf16x8*)(sK + krr * 128 + ((((s << 2) + lh) ^ (krr & 7)) << 4));
        sacc[i] = __builtin_amdgcn_mfma_f32_16x16x32_bf16(kf, qf, sacc[i], 0, 0, 0);
      }
    }

    // ---- softmax (lane owns one q) ----
    float sv[4][4];
    float tm = -1e30f;
#pragma unroll
    for (int i = 0; i < 4; ++i)
#pragma unroll
      for (int r = 0; r < 4; ++r) {
        float v = sacc[i][r] * 0.125f;
        if (k0 + i * 16 + lh * 4 + r >= DWT_) v = -1e30f;
        sv[i][r] = v;
        tm = fmaxf(tm, v);
      }
    tm = fmaxf(tm, __shfl_xor(tm, 16));
    tm = fmaxf(tm, __shfl_xor(tm, 32));
    float mn = fmaxf(m_, tm);
    float corr = __expf(m_ - mn);
    m_ = mn;
    float ts = 0.f;
    float p[4][4];
#pragma unroll
    for (int i = 0; i < 4; ++i)
#pragma unroll
      for (int r = 0; r < 4; ++r) {
        float e = __expf(sv[i][r] - mn);
        p[i][r] = e; ts += e;
      }
    ts += __shfl_xor(ts, 16);
    ts += __shfl_xor(ts, 32);
    l_ = l_ * corr + ts;

    // rescale accO (rows q-local = lh*4 + r; corr held by lane q-local)
#pragma unroll
    for (int r = 0; r < 4; ++r) {
      float cr = __shfl(corr, (lh << 2) + r);
#pragma unroll
      for (int jb = 0; jb < 4; ++jb) accO[jb][r] *= cr;
    }

    // gate + write P bf16 to wave-private LDS [q=l16][key]
#pragma unroll
    for (int i = 0; i < 4; ++i)
#pragma unroll
      for (int r = 0; r < 4; ++r) {
        float pv = p[i][r];
        int key = i * 16 + (lh << 2) + r;
        if (hg) pv *= sG[key];
        int slot = (key >> 3) ^ (l16 & 7);
        *(unsigned short*)(sPw + l16 * 128 + (slot << 4) + (key & 7) * 2) = f2bf(pv);
      }

    // ---- PV: A = P [16q][64key], B = V [key][d] from sV[d][key] ----
#pragma unroll
    for (int s = 0; s < 2; ++s) {
      bf16x8 pf = *(const bf16x8*)(sPw + l16 * 128 + ((((s << 2) + lh) ^ (l16 & 7)) << 4));
#pragma unroll
      for (int jb = 0; jb < 4; ++jb) {
        int vr = jb * 16 + l16;
        bf16x8 vf = *(const bf16x8*)(sV + vr * 128 + ((((s << 2) + lh) ^ (vr & 7)) << 4));
        accO[jb] = __builtin_amdgcn_mfma_f32_16x16x32_bf16(pf, vf, accO[jb], 0, 0, 0);
      }
    }
  }
#undef LOADT

  // ---- epilogue ----
  float linv = 1.f / l_;
#pragma unroll
  for (int r = 0; r < 4; ++r) {
    float li = __shfl(linv, (lh << 2) + r);
    int q = q0 + w * 16 + (lh << 2) + r;
    if (q >= DWT_) continue;
#pragma unroll
    for (int jb = 0; jb < 4; ++jb) {
      Oz[(size_t)(bD + q) * 512 + h64 + jb * 16 + l16] = f2bf(accO[jb][r] * li);
    }
  }
}

// ---------------------------------------------------------------------------
// fused LayerNorm, all residual inputs bf16 -> bf16 outputs (fp32 internal)
__global__ __launch_bounds__(256) void k_ln2(
    const unsigned short* __restrict__ llseq, const unsigned short* __restrict__ llout,
    const unsigned short* __restrict__ crossp,
    const unsigned short* __restrict__ lhseq, const unsigned short* __restrict__ lhout,
    const float* __restrict__ g, const float* __restrict__ beta,
    unsigned short* __restrict__ llf, unsigned short* __restrict__ lhf)
{
  __shared__ float red[256], red2[256];
  int row = blockIdx.x, tid = threadIdx.x, zz = blockIdx.y;
  const unsigned short* a  = zz ? lhseq : llseq;
  const unsigned short* b2 = zz ? lhout : llout;
  const unsigned short* c  = zz ? nullptr : crossp;
  const float* gg = g + zz * D_;
  const float* bb = beta + zz * D_;
  unsigned short* outp = zz ? lhf : llf;
  size_t base = (size_t)row * D_ + 2 * tid;
  unsigned av = *(const unsigned*)(a + base);
  unsigned bv = *(const unsigned*)(b2 + base);
  float v0 = bf2f((unsigned short)av) + bf2f((unsigned short)bv);
  float v1 = bf2f((unsigned short)(av >> 16)) + bf2f((unsigned short)(bv >> 16));
  if (c) {
    unsigned cv = *(const unsigned*)(c + base);
    v0 += bf2f((unsigned short)cv);
    v1 += bf2f((unsigned short)(cv >> 16));
  }
  red[tid] = v0 + v1; red2[tid] = v0 * v0 + v1 * v1;
  __syncthreads();
  for (int o = 128; o > 0; o >>= 1) {
    if (tid < o) { red[tid] += red[tid + o]; red2[tid] += red2[tid + o]; }
    __syncthreads();
  }
  float mu = red[0] / (float)D_;
  float var = red2[0] / (float)D_ - mu * mu;
  float rstd = rsqrtf(var + 1e-5f);
  float y0 = (v0 - mu) * rstd * gg[2 * tid] + bb[2 * tid];
  float y1 = (v1 - mu) * rstd * gg[2 * tid + 1] + bb[2 * tid + 1];
  *(unsigned*)(outp + base) = (unsigned)f2bf(y0) | ((unsigned)f2bf(y1) << 16);
}

// ---------------------------------------------------------------------------
// merged: blocks 0..1021 head_partial (head_W chunk staged through LDS, each
// byte fetched once; 192 compute threads own full (b, 4-pred) outputs);
// 1022..1533 recon with coalesced 16-o-chunk writes.
__global__ __launch_bounds__(512) void k_headrec(
    const float* __restrict__ llo, const float* __restrict__ lho,
    const float* __restrict__ llg, const float* __restrict__ lhg,
    const float* __restrict__ hw, float* __restrict__ part,
    const float* __restrict__ h, const float* __restrict__ g,
    float* __restrict__ outp)
{
  __shared__ float lds[8][520];   // +8 pad: 8 pb-broadcast rows spread banks
  __shared__ float sW[6144];      // 64 k-rows x 96 preds (24KB chunk)
  int bid = blockIdx.x, tid = threadIdx.x;
  if (bid < 2 * DWT_) {
    int x = bid;
    int branch = x / DWT_, t = x % DWT_;
    const float* seq = branch ? lho : llo;
    const float* gt  = branch ? lhg : llg;
    for (int i = tid; i < 4096; i += 512) {
      int b = i >> 9, d = i & 511;
      lds[b][d] = seq[((size_t)b * DWT_ + t) * D_ + d] * gt[(size_t)t * D_ + d];
    }
    const bool act = tid < 192;
    const int pb_ = tid / 24, j = tid % 24;   // b 0..7, pred-quad 0..23
    f32x4 acc = (f32x4){0.f, 0.f, 0.f, 0.f};
    const float* hwx = hw + (size_t)x * (D_ * 96);
    for (int c = 0; c < 8; ++c) {
      __syncthreads();
      // cooperative stage of 64 k-rows (6144 floats), perfectly coalesced
      {
        const float* src = hwx + (size_t)c * 6144 + tid * 12;
        float4 v0 = *(const float4*)(src);
        float4 v1 = *(const float4*)(src + 4);
        float4 v2 = *(const float4*)(src + 8);
        *(float4*)&sW[tid * 12]     = v0;
        *(float4*)&sW[tid * 12 + 4] = v1;
        *(float4*)&sW[tid * 12 + 8] = v2;
      }
      __syncthreads();
      if (act) {
        int k0 = c * 64;
#pragma unroll 8
        for (int k = 0; k < 64; ++k) {
          float s = lds[pb_][k0 + k];
          float4 wv = *(const float4*)&sW[k * 96 + j * 4];
          acc[0] += s * wv.x; acc[1] += s * wv.y;
          acc[2] += s * wv.z; acc[3] += s * wv.w;
        }
      }
    }
    if (act)
      *(f32x4*)&part[(size_t)x * 768 + pb_ * 96 + j * 4] = acc;
  } else {
    int rid = bid - 2 * DWT_;
    int b = rid >> 6, ot = rid & 63;
    int o0 = ot << 4;
    int d = tid;
    float h4[4], g4[4];
#pragma unroll
    for (int k = 0; k < 4; ++k) { h4[k] = h[d * 4 + k]; g4[k] = g[d * 4 + k]; }
    int tb = (o0 >> 1) - 1;
    float rl[10], rh[10];
#pragma unroll
    for (int k = 0; k < 10; ++k) {
      int t = tb + k;
      bool ok = (t >= 0 && t < DWT_);
      size_t ix = ((size_t)(b * DWT_ + (ok ? t : 0))) * D_ + d;
      rl[k] = ok ? llo[ix] : 0.f;
      rh[k] = ok ? lho[ix] : 0.f;
    }
    float* ob = outp + ((size_t)(b * D_ + d)) * RECON_LEN + o0;
#pragma unroll
    for (int j2 = 0; j2 < 16; ++j2) {
      int o = o0 + j2;
      float acc;
      if ((j2 & 1) == 0) {
        int ix = (j2 >> 1) + 1;
        acc = rl[ix - 1] * h4[3] + rh[ix - 1] * g4[3] + rl[ix] * h4[1] + rh[ix] * g4[1];
      } else {
        int ix = ((j2 - 1) >> 1) + 1;
        acc = rl[ix] * h4[2] + rh[ix] * g4[2] + rl[ix + 1] * h4[0] + rh[ix + 1] * g4[0];
      }
      if (o < RECON_LEN) ob[j2] = acc;
    }
  }
}

// wave-per-(b,p) reduction over 1022 chunks (768 waves of parallelism)
__global__ __launch_bounds__(256) void k_head_final(const float* __restrict__ part,
    const float* __restrict__ hb, const float* __restrict__ rw,
    const float* __restrict__ rb, const float* __restrict__ meanp,
    const float* __restrict__ stdp, float* __restrict__ preds)
{
  int wv = (blockIdx.x << 2) + (threadIdx.x >> 6);
  int lane = threadIdx.x & 63;
  if (wv >= 768) return;
  int b = wv / 96, p = wv - b * 96;
  float s = 0.f;
  for (int c = lane; c < 2 * DWT_; c += 64) s += part[(size_t)c * 768 + b * 96 + p];
#pragma unroll
  for (int off = 32; off; off >>= 1) s += __shfl_xor(s, off);
  if (lane == 0) {
    float acc = s + hb[p];
    preds[b * 96 + p] = (acc - rb[0]) / (rw[0] + 1e-10f) * stdp[b] + meanp[b];
  }
}

// ---------------------------------------------------------------------------
extern "C" void kernel_launch(void* const* d_in, const int* in_sizes, int n_in,
                              void* d_out, int out_size, void* d_ws, size_t ws_size,
                              hipStream_t stream)
{
  const float* x       = (const float*)d_in[0];
  const float* revin_w = (const float*)d_in[1];
  const float* revin_b = (const float*)d_in[2];
  const float* patch_W = (const float*)d_in[3];
  const float* patch_b = (const float*)d_in[4];
  const float* pos_emb = (const float*)d_in[5];
  const float* dwt_h   = (const float*)d_in[6];
  const float* dwt_g   = (const float*)d_in[7];
  const float* raw_tau = (const float*)d_in[8];
  const float* attn_W  = (const float*)d_in[9];
  const float* attn_b  = (const float*)d_in[10];
  const float* mlp_W1  = (const float*)d_in[11];
  const float* mlp_b1  = (const float*)d_in[12];
  const float* mlp_W2  = (const float*)d_in[13];
  const float* mlp_b2  = (const float*)d_in[14];
  const float* ln_g    = (const float*)d_in[15];
  const float* ln_b    = (const float*)d_in[16];
  const float* ll_gate = (const float*)d_in[17];
  const float* lh_gate = (const float*)d_in[18];
  const float* head_W  = (const float*)d_in[19];
  const float* head_b  = (const float*)d_in[20];

  float* ws  = (float*)d_ws;
  float* out = (float*)d_out;

  float* meanp = ws + WS_MEAN;
  float* stdp  = ws + WS_STD;
  float* xn    = ws + WS_XN;
  float* pseq  = ws + WS_PSEQ;
  float* gateb = ws + WS_GATE;
  float* llo   = ws + WS_LLO;
  float* lho   = ws + WS_LHO;
  float* part  = ws + WS_PART;

  unsigned short* llseq16 = (unsigned short*)(ws + WS_LLSEQ);
  unsigned short* lhseq16 = (unsigned short*)(ws + WS_LHSEQ);
  unsigned short* cross16 = (unsigned short*)(ws + WS_CROSS);
  unsigned short* llf16 = (unsigned short*)(ws + WS_LLF);
  unsigned short* lhf16 = (unsigned short*)(ws + WS_LHF);
  unsigned short* Qb16  = (unsigned short*)(ws + WS_QB);
  unsigned short* Kb16  = (unsigned short*)(ws + WS_KB);
  unsigned short* Vt16  = (unsigned short*)(ws + WS_VT);
  unsigned short* Ob16  = (unsigned short*)(ws + WS_OB);
  unsigned short* hid16 = (unsigned short*)(ws + WS_HID2);
  unsigned short* llout16 = (unsigned short*)(ws + WS_LLO16);
  unsigned short* lhout16 = llout16 + 2093056;

  unsigned short* wt  = (unsigned short*)(ws + WS_WT);    // bf16 weights (own region)
  unsigned short* w1t = wt + 12 * 262144;                 // 2 x [2048][512]
  unsigned short* w2t = w1t + 2 * 1048576;                // 2 x [512][2048]

  // ---- stage 0: RevIN + (patch|weight-prep) + (transpose|DWT+gate) ----
  k_revin<<<8, 256, 0, stream>>>(x, revin_w, revin_b, meanp, stdp, xn);
  k_pw<<<8184 + 7168, 512, 0, stream>>>(xn, patch_W, patch_b, pos_emb, pseq,
                                        attn_W, mlp_W1, mlp_W2, wt, w1t, w2t);
  k_td<<<4096 + 256, 512, 0, stream>>>(pseq, out + PATCHES_O, dwt_h, dwt_g,
                                       llseq16, lhseq16, out + OUT_LL_O,
                                       out + OUT_LH_O, raw_tau, gateb);

  // ---- stage 1: LL + LH MHAs batched ----
  k_gemm_mfma<64,3><<<dim3(12, 64, 2), 256, 0, stream>>>(
      llseq16, llseq16, lhseq16, lhseq16, wt, attn_b, nullptr, nullptr,
      Qb16, Kb16, Vt16, MR_, 1536, D_, 0, 4 * 262144, 2048);
  k_mattn<<<dim3(64, 8, 2), 256, 0, stream>>>(Qb16, Kb16, Vt16, gateb, Ob16);
  k_gemm_mfma<64,1><<<dim3(4, 64, 2), 256, 0, stream>>>(
      Ob16, nullptr, Ob16 + (size_t)2093056, nullptr, wt + 3 * 262144,
      attn_b + 1536, nullptr, nullptr, llout16, lhout16, nullptr,
      MR_, D_, D_, 0, 4 * 262144, 2048);

  // ---- cross MHA: Q from llout16, K/V from lhout16 ----
  k_gemm_mfma<64,3><<<dim3(12, 64, 1), 256, 0, stream>>>(
      llout16, lhout16, nullptr, nullptr, wt + 8 * 262144, attn_b + 2 * 2048,
      nullptr, nullptr, Qb16, Kb16, Vt16, MR_, 1536, D_, 0, 0, 0);
  k_mattn<<<dim3(64, 8, 1), 256, 0, stream>>>(Qb16, Kb16, Vt16, nullptr, Ob16);
  k_gemm_mfma<64,1><<<dim3(4, 64, 1), 256, 0, stream>>>(
      Ob16, nullptr, nullptr, nullptr, wt + 11 * 262144, attn_b + 2 * 2048 + 1536,
      nullptr, nullptr, cross16, nullptr, nullptr, MR_, D_, D_, 0, 0, 0);

  // ---- stage 2: fused LN (bf16) + batched MLP ----
  k_ln2<<<dim3(MR_, 2), 256, 0, stream>>>(llseq16, llout16, cross16,
                                          lhseq16, lhout16, ln_g, ln_b,
                                          llf16, lhf16);
  k_gemm_mfma<128,1><<<dim3(16, 32, 2), 256, 0, stream>>>(
      llf16, nullptr, lhf16, nullptr, w1t, mlp_b1, nullptr, nullptr,
      hid16, hid16 + (size_t)4088 * 2048, nullptr, MR_, DFF_, D_, 1,
      1048576, 2048);
  k_gemm_mfma<64,0,1><<<dim3(4, 64, 2), 256, 0, stream>>>(
      hid16, nullptr, hid16 + (size_t)4088 * 2048, nullptr, w2t, mlp_b2,
      llf16, lhf16, llo, lho, nullptr, MR_, D_, DFF_, 0, 1048576, 512);

  // ---- stage 3: (head_partial | recon) merged + head_final ----
  k_headrec<<<2 * DWT_ + 512, 512, 0, stream>>>(llo, lho, ll_gate, lh_gate,
                                                head_W, part, dwt_h, dwt_g,
                                                out + RECON_O);
  k_head_final<<<192, 256, 0, stream>>>(part, head_b, revin_w, revin_b, meanp, stdp,
                                        out + PREDS_O);
}